// Round 2
// baseline (1540.350 us; speedup 1.0000x reference)
//
#include <hip/hip_runtime.h>
#include <hip/hip_bf16.h>

#define NN 50000
#define NE 800000
#define FD 80
#define NGR 1024
#define NF 9

using bf16 = __hip_bfloat16;
static __device__ __forceinline__ float b2f(bf16 v){ return __bfloat162float(v); }
static __device__ __forceinline__ bf16 f2b(float v){ return __float2bfloat16(v); }

// read weight element i: bf16 layout (flag=0) or f32 layout (flag=1)
static __device__ __forceinline__ float rdw(const void* p, int i, int fl){
  return fl ? ((const float*)p)[i] : b2f(((const bf16*)p)[i]);
}

// ------------------------------------------------------------------ utility
__global__ void k_zero(int* __restrict__ p, int n){
  int t = blockIdx.x*256 + threadIdx.x;
  if (t < n) p[t] = 0;
}

// dtype probe: if buffer (really f32) read as bf16 shows huge/NaN values -> flag=1
__global__ void k_probe(const void* __restrict__ emb, int n, int* __restrict__ flag){
  int t = blockIdx.x*256 + threadIdx.x;
  if (t >= n) return;
  float v = b2f(((const bf16*)emb)[t]);
  if (!(fabsf(v) < 1e4f)) atomicOr(flag, 1);   // catches inf/NaN too
}

// ------------------------------------------------------------------ weight prep
// B1[i][k][c] (stride 192): c<80 -> pre_W[i][k][c], 80<=c<160 -> pre_W[i][80+k][c-80]
__global__ void k_prep_B1(const void* __restrict__ preW, const void* __restrict__ preb,
                          const int* __restrict__ flag,
                          float* __restrict__ B1, float* __restrict__ bias1){
  int fl = flag[0];
  int t = blockIdx.x*256 + threadIdx.x;
  if (t < 4*192){
    int c = t % 192, i = t / 192;
    bias1[t] = (c < 80) ? rdw(preb, i*80 + c, fl) : 0.f;
  }
  if (t >= 4*80*192) return;
  int c = t % 192;
  int k = (t/192) % 80;
  int i = t / (192*80);
  float v = 0.f;
  if (c < 80)       v = rdw(preW, (i*160 + k)*80 + c, fl);
  else if (c < 160) v = rdw(preW, (i*160 + 80 + k)*80 + (c - 80), fl);
  B1[t] = v;
}

// B2[i][k][c] (stride 256): Wfold = post_W @ lin_W, cols scaled by gamma*rsqrt(var+eps).
// rows k: 0..79 h part (P only); 80..399 agg part: P rows 80..399, Q rows 400..719, R rows 720..1039.
// cols: 0..79 P, 80..159 Q, 160..239 R, 240..255 zero pad.
__global__ void k_prep_B2(const void* __restrict__ postW, const void* __restrict__ linW,
                          const void* __restrict__ gamma, const void* __restrict__ var,
                          const int* __restrict__ flag, float* __restrict__ B2){
  int fl = flag[0];
  int t = blockIdx.x*256 + threadIdx.x;
  if (t >= 4*400*256) return;
  int c = t & 255;
  int k = (t >> 8) % 400;
  int i = t / (400*256);
  float v = 0.f;
  if (c < 240){
    int blk = c / 80, f = c - blk*80;
    int row = -1;
    if (k < 80){ if (blk == 0) row = k; }
    else{
      int ar = k - 80;
      row = (blk == 0) ? (80 + ar) : (blk == 1) ? (400 + ar) : (720 + ar);
    }
    if (row >= 0){
      float s = 0.f;
      #pragma unroll 8
      for (int j = 0; j < 80; j++)
        s += rdw(postW, (i*1040 + row)*80 + j, fl) * rdw(linW, i*6400 + j*80 + f, fl);
      float gs = rdw(gamma, i*80 + f, fl) * rsqrtf(rdw(var, i*80 + f, fl) + 1e-5f);
      v = s * gs;
    }
  }
  B2[t] = v;
}

__global__ void k_prep_bias2(const void* __restrict__ postb, const void* __restrict__ linW,
                             const void* __restrict__ linb, const void* __restrict__ gamma,
                             const void* __restrict__ beta, const void* __restrict__ mu,
                             const void* __restrict__ var, const int* __restrict__ flag,
                             float* __restrict__ bias2){
  int fl = flag[0];
  int t = blockIdx.x*256 + threadIdx.x;
  if (t >= 4*80) return;
  int i = t / 80, f = t - i*80;
  float s = 0.f;
  for (int j = 0; j < 80; j++)
    s += rdw(postb, i*80 + j, fl) * rdw(linW, (i*80 + j)*80 + f, fl);
  s += rdw(linb, t, fl);
  float gs = rdw(gamma, t, fl) * rsqrtf(rdw(var, t, fl) + 1e-5f);
  bias2[t] = (s - rdw(mu, t, fl)) * gs + rdw(beta, t, fl);
}

// ------------------------------------------------------------------ graph prep
__global__ void k_atom(const int* __restrict__ x, const void* __restrict__ emb,
                       const int* __restrict__ flag, float* __restrict__ h){
  int fl = flag[0];
  int gid = blockIdx.x*256 + threadIdx.x;
  if (gid >= NN*FD) return;
  int n = gid / FD, f = gid - n*FD;
  float s = 0.f;
  #pragma unroll
  for (int c = 0; c < NF; c++){
    int row = x[n*NF + c];
    s += rdw(emb, (c*119 + row)*FD + f, fl);
  }
  h[gid] = s;
}

__global__ void k_deg(const int* __restrict__ ei, int* __restrict__ deg){
  int e = blockIdx.x*256 + threadIdx.x;
  if (e < NE) atomicAdd(&deg[ei[NE + e]], 1);
}

// simple bulletproof exclusive scan: 256 threads, serial chunks + serial chunk-scan
__global__ __launch_bounds__(256) void k_scan(const int* __restrict__ deg,
                                              int* __restrict__ rowptr){
  __shared__ int csum[256];
  const int CH = (NN + 255)/256;      // 196
  int t = threadIdx.x;
  int lo = t*CH, hi = lo + CH; if (hi > NN) hi = NN; if (lo > NN) lo = NN;
  int s = 0;
  for (int i = lo; i < hi; i++) s += deg[i];
  csum[t] = s;
  __syncthreads();
  if (t == 0){
    int run = 0;
    for (int i = 0; i < 256; i++){ int v = csum[i]; csum[i] = run; run += v; }
    rowptr[NN] = run;                 // == NE
  }
  __syncthreads();
  int run = csum[t];
  for (int i = lo; i < hi; i++){ rowptr[i] = run; run += deg[i]; }
}

__global__ void k_scalars(const int* __restrict__ deg, const void* __restrict__ avgp,
                          const int* __restrict__ flag,
                          float* __restrict__ scf, float* __restrict__ invf){
  int fl = flag[0];
  int n = blockIdx.x*256 + threadIdx.x;
  if (n >= NN) return;
  int d = deg[n];
  float degc = (float)(d > 0 ? d : 1);
  float logd = logf(degc + 1.f);
  float avg = rdw(avgp, 0, fl);
  scf[n] = logd / avg;
  invf[n] = avg / logd;
}

__global__ void k_scatter(const int* __restrict__ ei, const int* __restrict__ rowptr,
                          int* __restrict__ cursor, int* __restrict__ colidx){
  int e = blockIdx.x*256 + threadIdx.x;
  if (e >= NE) return;
  int d = ei[NE + e];
  int pos = rowptr[d] + atomicAdd(&cursor[d], 1);
  colidx[pos] = ei[e];
}

// ------------------------------------------------------------------ GEMM
// C[bf16, stride Cstride, cols<Ccols] = A @ B + bias.
// MODE 0: A f32 row-major [M,80]. MODE 2: k<80 from h(f32,stride 80), k>=80 from agg(bf16,stride 320).
template<int MODE>
__global__ __launch_bounds__(256) void k_gemm(
    const float* __restrict__ A, const void* __restrict__ A2,
    const float* __restrict__ B, int Bstride,
    const float* __restrict__ bias,
    bf16* __restrict__ C, int Cstride, int Ccols, int M, int K)
{
  __shared__ float As[16][68];
  __shared__ float Bs[16][64];
  const int tid = threadIdx.x;
  const int tx = tid & 15, ty = tid >> 4;
  const int row0 = blockIdx.x * 64;
  const int col0 = blockIdx.y * 64;
  float acc[4][4] = {{0.f}};
  for (int k0 = 0; k0 < K; k0 += 16){
    int ka = tid & 15;
    int ma = tid >> 4;
    #pragma unroll
    for (int mm = 0; mm < 4; mm++){
      int m = ma + mm*16;
      int row = row0 + m;
      float v = 0.f;
      if (row < M){
        int kg = k0 + ka;
        if (MODE == 0) v = A[row*80 + kg];
        else           v = (kg < 80) ? A[row*80 + kg]
                                     : b2f(((const bf16*)A2)[row*320 + (kg - 80)]);
      }
      As[ka][m] = v;
    }
    int nb = tid & 63;
    int kb = tid >> 6;
    #pragma unroll
    for (int kk = 0; kk < 4; kk++)
      Bs[kb + kk*4][nb] = B[(k0 + kb + kk*4)*Bstride + col0 + nb];
    __syncthreads();
    #pragma unroll
    for (int kk = 0; kk < 16; kk++){
      float4 a4 = *(const float4*)&As[kk][ty*4];
      float4 b4 = *(const float4*)&Bs[kk][tx*4];
      float av[4] = {a4.x, a4.y, a4.z, a4.w};
      float bv[4] = {b4.x, b4.y, b4.z, b4.w};
      #pragma unroll
      for (int r = 0; r < 4; r++)
        #pragma unroll
        for (int c = 0; c < 4; c++)
          acc[r][c] += av[r] * bv[c];
    }
    __syncthreads();
  }
  #pragma unroll
  for (int r = 0; r < 4; r++){
    int row = row0 + ty*4 + r;
    if (row >= M) continue;
    #pragma unroll
    for (int c = 0; c < 4; c++){
      int col = col0 + tx*4 + c;
      if (col >= Ccols) continue;
      float bval = bias ? bias[col] : 0.f;
      C[row*Cstride + col] = f2b(acc[r][c] + bval);
    }
  }
}

// ------------------------------------------------------------------ aggregation
// U(bf16, stride 240): a = U[n*240+f], b = U[n*240+80+f]. agg(bf16, stride 320) = [mean|mn|mx|std]
__global__ void k_agg(const bf16* __restrict__ U, const int* __restrict__ rowptr,
                      const int* __restrict__ colidx, bf16* __restrict__ agg)
{
  int gid = blockIdx.x*256 + threadIdx.x;
  if (gid >= NN*FD) return;
  int n = gid / FD, f = gid - n*FD;
  int rs = rowptr[n], re = rowptr[n+1];
  float a = b2f(U[n*240 + f]);
  float sb = 0.f, sbb = 0.f;
  float bmin = 1e30f, bmax = -1e30f;
  for (int e = rs; e < re; e++){
    int s = colidx[e];
    float bv = b2f(U[s*240 + 80 + f]);
    sb += bv; sbb += bv*bv;
    bmin = fminf(bmin, bv); bmax = fmaxf(bmax, bv);
  }
  int deg = re - rs;
  float degc = (float)(deg > 0 ? deg : 1);
  float mean = ((float)deg * a + sb) / degc;
  float s2 = (float)deg * a * a + 2.f*a*sb + sbb;
  float var = s2/degc - mean*mean;
  float stdv = sqrtf(fmaxf(var, 0.f) + 1e-5f);
  float mn = (deg > 0) ? a + bmin : 0.f;
  float mx = (deg > 0) ? a + bmax : 0.f;
  bf16* ag = agg + n*320 + f;
  ag[0]   = f2b(mean);
  ag[80]  = f2b(mn);
  ag[160] = f2b(mx);
  ag[240] = f2b(stdv);
}

// h += relu(P + sc*Q + inv*R + bias2)
__global__ void k_combine(const bf16* __restrict__ U, const float* __restrict__ b2v,
                          const float* __restrict__ scf, const float* __restrict__ invf,
                          float* __restrict__ h){
  int gid = blockIdx.x*256 + threadIdx.x;
  if (gid >= NN*FD) return;
  int n = gid / FD, f = gid - n*FD;
  const bf16* xr = U + n*240;
  float o = b2f(xr[f]) + scf[n]*b2f(xr[80 + f]) + invf[n]*b2f(xr[160 + f]) + b2v[f];
  h[gid] += fmaxf(o, 0.f);
}

// ------------------------------------------------------------------ pooling + head
__global__ void k_pool(const float* __restrict__ h, const int* __restrict__ batch,
                       float* __restrict__ gsum, float* __restrict__ gcnt){
  int gid = blockIdx.x*256 + threadIdx.x;
  if (gid >= NN*FD) return;
  int n = gid / FD, f = gid - n*FD;
  int g = batch[n];
  atomicAdd(&gsum[g*FD + f], h[gid]);
  if (f == 0) atomicAdd(&gcnt[g], 1.f);
}

__global__ void k_mlp(const float* __restrict__ gsum, const float* __restrict__ gcnt,
                      const void* __restrict__ mlpW, const void* __restrict__ mlpb,
                      const int* __restrict__ flag, void* __restrict__ outp){
  int fl = flag[0];
  int g = blockIdx.x*256 + threadIdx.x;
  if (g >= NGR) return;
  float cnt = fmaxf(gcnt[g], 1.f);
  float s = 0.f;
  for (int f = 0; f < FD; f++) s += gsum[g*FD + f] * rdw(mlpW, f, fl);
  float r = s / cnt + rdw(mlpb, 0, fl);
  if (fl) ((float*)outp)[g] = r;
  else    ((bf16*)outp)[g] = f2b(r);
}

// ------------------------------------------------------------------ launch
extern "C" void kernel_launch(void* const* d_in, const int* in_sizes, int n_in,
                              void* d_out, int out_size, void* d_ws, size_t ws_size,
                              hipStream_t stream)
{
  const int*  x     = (const int*) d_in[0];
  const int*  ei    = (const int*) d_in[1];
  const int*  batch = (const int*) d_in[2];
  const void* avgp  = d_in[3];
  const void* aemb  = d_in[4];
  const void* preW  = d_in[5];
  const void* preb  = d_in[6];
  const void* postW = d_in[7];
  const void* postb = d_in[8];
  const void* linW  = d_in[9];
  const void* linb  = d_in[10];
  const void* bng   = d_in[11];
  const void* bnb   = d_in[12];
  const void* bnm   = d_in[13];
  const void* bnv   = d_in[14];
  const void* mlpW  = d_in[15];
  const void* mlpb  = d_in[16];

  char* w = (char*)d_ws;
  // zero region (contiguous from 0): deg, cursor, gsum, gcnt, flag
  int*   deg    = (int*)  (w + 0);            //   200,000
  int*   cursor = (int*)  (w + 200000);       //   200,000
  float* gsum   = (float*)(w + 400000);       //   327,680
  float* gcnt   = (float*)(w + 727680);       //     4,096
  int*   flag   = (int*)  (w + 731776);       //       256  -> zero 732,032 B = 183,008 ints
  int*   rowptr = (int*)  (w + 732032);       //   200,064
  int*   colidx = (int*)  (w + 932096);       // 3,200,000
  float* scf    = (float*)(w + 4132096);      //   200,000
  float* invf   = (float*)(w + 4332096);      //   200,000
  float* B1     = (float*)(w + 4532096);      //   245,760
  float* bias1  = (float*)(w + 4777856);      //     3,072
  float* B2     = (float*)(w + 4780928);      // 1,638,400
  float* bias2  = (float*)(w + 6419328);      //     1,280
  float* h      = (float*)(w + 6420608);      // 16,000,000 (f32 [N,80])
  bf16*  U      = (bf16*) (w + 22420608);     // 24,000,000 (bf16 [N,240]: ab then PQR)
  bf16*  agg    = (bf16*) (w + 46420608);     // 32,000,000 (bf16 [N,320])
  // total: 78,420,608 B

  k_zero <<<(183008 + 255)/256, 256, 0, stream>>>((int*)w, 183008);
  k_probe<<<(9*119*80 + 255)/256, 256, 0, stream>>>(aemb, 9*119*80, flag);

  k_prep_B1   <<<(4*80*192 + 255)/256, 256, 0, stream>>>(preW, preb, flag, B1, bias1);
  k_prep_B2   <<<(4*400*256 + 255)/256, 256, 0, stream>>>(postW, linW, bng, bnv, flag, B2);
  k_prep_bias2<<<2, 256, 0, stream>>>(postb, linW, linb, bng, bnb, bnm, bnv, flag, bias2);

  k_atom   <<<(NN*FD + 255)/256, 256, 0, stream>>>(x, aemb, flag, h);
  k_deg    <<<(NE + 255)/256, 256, 0, stream>>>(ei, deg);
  k_scan   <<<1, 256, 0, stream>>>(deg, rowptr);
  k_scalars<<<(NN + 255)/256, 256, 0, stream>>>(deg, avgp, flag, scf, invf);
  k_scatter<<<(NE + 255)/256, 256, 0, stream>>>(ei, rowptr, cursor, colidx);

  dim3 g1((NN + 63)/64, 3);
  dim3 g2((NN + 63)/64, 4);
  for (int i = 0; i < 4; i++){
    k_gemm<0><<<g1, 256, 0, stream>>>(h, nullptr, B1 + i*80*192, 192,
                                      bias1 + i*192, U, 240, 192, NN, 80);
    k_agg    <<<(NN*FD + 255)/256, 256, 0, stream>>>(U, rowptr, colidx, agg);
    k_gemm<2><<<g2, 256, 0, stream>>>(h, agg, B2 + i*400*256, 256,
                                      nullptr, U, 240, 240, NN, 400);
    k_combine<<<(NN*FD + 255)/256, 256, 0, stream>>>(U, bias2 + i*80, scf, invf, h);
  }

  k_pool<<<(NN*FD + 255)/256, 256, 0, stream>>>(h, batch, gsum, gcnt);
  k_mlp <<<(NGR + 255)/256, 256, 0, stream>>>(gsum, gcnt, mlpW, mlpb, flag, d_out);
}

// Round 3
// 1160.247 us; speedup vs baseline: 1.3276x; 1.3276x over previous
//
#include <hip/hip_runtime.h>
#include <hip/hip_bf16.h>

#define NN 50000
#define NE 800000
#define FD 80
#define NGR 1024
#define NF 9

using bf16 = __hip_bfloat16;
typedef __attribute__((ext_vector_type(8))) short bf16x8;
typedef __attribute__((ext_vector_type(4))) float f32x4;

static __device__ __forceinline__ float b2f(bf16 v){ return __bfloat162float(v); }
static __device__ __forceinline__ bf16 f2b(float v){ return __float2bfloat16(v); }
static __device__ __forceinline__ float rdw(const void* p, int i, int fl){
  return fl ? ((const float*)p)[i] : b2f(((const bf16*)p)[i]);
}
static __device__ __forceinline__ unsigned pk(float a, float b){
  bf16 x = f2b(a), y = f2b(b);
  return (unsigned)*(unsigned short*)&x | ((unsigned)*(unsigned short*)&y << 16);
}

// ------------------------------------------------------------------ utility
__global__ void k_zero(int* __restrict__ p, int n){
  int t = blockIdx.x*256 + threadIdx.x;
  if (t < n) p[t] = 0;
}

__global__ void k_probe(const void* __restrict__ emb, int n, int* __restrict__ flag){
  int t = blockIdx.x*256 + threadIdx.x;
  if (t >= n) return;
  float v = b2f(((const bf16*)emb)[t]);
  if (!(fabsf(v) < 1e4f)) atomicOr(flag, 1);
}

// ------------------------------------------------------------------ weight prep
__global__ void k_cvt_pw(const void* __restrict__ postW, const int* __restrict__ flag,
                         bf16* __restrict__ pwb){
  int fl = flag[0];
  int t = blockIdx.x*256 + threadIdx.x;
  if (t < 4*1040*80) pwb[t] = f2b(rdw(postW, t, fl));
}

// Btl[i][c][j] (96-k): scaled linW^T: linW[j][c]*gs[c], zero pad j>=80
__global__ void k_prep_lin(const void* __restrict__ linW, const void* __restrict__ gamma,
                           const void* __restrict__ var, const int* __restrict__ flag,
                           bf16* __restrict__ Btl){
  int fl = flag[0];
  int t = blockIdx.x*256 + threadIdx.x;
  if (t >= 4*80*96) return;
  int j = t % 96;
  int c = (t/96) % 80;
  int i = t/(96*80);
  float v = 0.f;
  if (j < 80){
    float gs = rdw(gamma, i*80 + c, fl) * rsqrtf(rdw(var, i*80 + c, fl) + 1e-5f);
    v = rdw(linW, i*6400 + j*80 + c, fl) * gs;
  }
  Btl[t] = f2b(v);
}

// Bt1[i][c][k] (c<160 cols, 96-k): col c<80 -> preW[i][k][c], else preW[i][80+k][c-80]
__global__ void k_prep_Bt1(const void* __restrict__ preW, const void* __restrict__ preb,
                           const int* __restrict__ flag,
                           bf16* __restrict__ Bt1, float* __restrict__ bias1){
  int fl = flag[0];
  int t = blockIdx.x*256 + threadIdx.x;
  if (t >= 4*160*96) return;
  int k = t % 96;
  int c = (t/96) % 160;
  int i = t/(96*160);
  float v = 0.f;
  if (k < 80)
    v = (c < 80) ? rdw(preW, (i*160 + k)*80 + c, fl)
                 : rdw(preW, (i*160 + 80 + k)*80 + (c - 80), fl);
  Bt1[t] = f2b(v);
  if (k == 0) bias1[i*160 + c] = (c < 80) ? rdw(preb, i*80 + c, fl) : 0.f;
}

// Bt2[i][c][k] (c<240 cols, 416-k) from Wf (f32 [i][1040][80]).
// c<80 (P,f=c): k<400 -> Wf[k][f]. 80<=c<160 (Q): k in[80,400) -> Wf[400+k-80][f].
// 160<=c<240 (R): k in[80,400) -> Wf[720+k-80][f]. else 0.
__global__ void k_prep_Bt2(const float* __restrict__ Wf, bf16* __restrict__ Bt2){
  int t = blockIdx.x*256 + threadIdx.x;
  if (t >= 4*240*416) return;
  int k = t % 416;
  int c = (t/416) % 240;
  int i = t/(416*240);
  float v = 0.f;
  if (k < 400){
    int blk = c/80, f = c - blk*80;
    if (blk == 0) v = Wf[(i*1040 + k)*80 + f];
    else if (k >= 80){
      int row = (blk == 1 ? 400 : 720) + (k - 80);
      v = Wf[(i*1040 + row)*80 + f];
    }
  }
  Bt2[t] = f2b(v);
}

__global__ void k_prep_bias2(const void* __restrict__ postb, const void* __restrict__ linW,
                             const void* __restrict__ linb, const void* __restrict__ gamma,
                             const void* __restrict__ beta, const void* __restrict__ mu,
                             const void* __restrict__ var, const int* __restrict__ flag,
                             float* __restrict__ bias2){
  int fl = flag[0];
  int t = blockIdx.x*256 + threadIdx.x;
  if (t >= 4*80) return;
  int i = t / 80, f = t - i*80;
  float s = 0.f;
  for (int j = 0; j < 80; j++)
    s += rdw(postb, i*80 + j, fl) * rdw(linW, (i*80 + j)*80 + f, fl);
  s += rdw(linb, t, fl);
  float gs = rdw(gamma, t, fl) * rsqrtf(rdw(var, t, fl) + 1e-5f);
  bias2[t] = (s - rdw(mu, t, fl)) * gs + rdw(beta, t, fl);
}

// ------------------------------------------------------------------ graph prep
__global__ void k_atom(const int* __restrict__ x, const void* __restrict__ emb,
                       const int* __restrict__ flag, float* __restrict__ h){
  int fl = flag[0];
  int gid = blockIdx.x*256 + threadIdx.x;
  if (gid >= NN*FD) return;
  int n = gid / FD, f = gid - n*FD;
  float s = 0.f;
  #pragma unroll
  for (int c = 0; c < NF; c++){
    int row = x[n*NF + c];
    s += rdw(emb, (c*119 + row)*FD + f, fl);
  }
  h[gid] = s;
}

__global__ void k_deg(const int* __restrict__ ei, int* __restrict__ deg){
  int e = blockIdx.x*256 + threadIdx.x;
  if (e < NE) atomicAdd(&deg[ei[NE + e]], 1);
}

__global__ __launch_bounds__(256) void k_scan(const int* __restrict__ deg,
                                              int* __restrict__ rowptr){
  __shared__ int csum[256];
  const int CH = (NN + 255)/256;
  int t = threadIdx.x;
  int lo = t*CH, hi = lo + CH; if (hi > NN) hi = NN; if (lo > NN) lo = NN;
  int s = 0;
  for (int i = lo; i < hi; i++) s += deg[i];
  csum[t] = s;
  __syncthreads();
  if (t == 0){
    int run = 0;
    for (int i = 0; i < 256; i++){ int v = csum[i]; csum[i] = run; run += v; }
    rowptr[NN] = run;
  }
  __syncthreads();
  int run = csum[t];
  for (int i = lo; i < hi; i++){ rowptr[i] = run; run += deg[i]; }
}

__global__ void k_scalars(const int* __restrict__ deg, const void* __restrict__ avgp,
                          const int* __restrict__ flag,
                          float* __restrict__ scf, float* __restrict__ invf){
  int fl = flag[0];
  int n = blockIdx.x*256 + threadIdx.x;
  if (n >= NN) return;
  int d = deg[n];
  float degc = (float)(d > 0 ? d : 1);
  float logd = logf(degc + 1.f);
  float avg = rdw(avgp, 0, fl);
  scf[n] = logd / avg;
  invf[n] = avg / logd;
}

__global__ void k_scatter(const int* __restrict__ ei, const int* __restrict__ rowptr,
                          int* __restrict__ cursor, int* __restrict__ colidx){
  int e = blockIdx.x*256 + threadIdx.x;
  if (e >= NE) return;
  int d = ei[NE + e];
  int pos = rowptr[d] + atomicAdd(&cursor[d], 1);
  colidx[pos] = ei[e];
}

// ------------------------------------------------------------------ MFMA GEMM
// C[M x Ncols] = A[M x K] @ B[K x Ncols] + bias. 128x128 tile, 4 waves.
// A rows: k<KA from A1 (f32 if AF32 else bf16, stride s1); KA<=k<KA+KB from A2 (bf16, s2); else 0.
// Bt is B^T bf16 [Ncols][Bts], rows fully padded to K.
template<int AF32, int F32OUT>
__global__ __launch_bounds__(256) void k_mgemm(
    const void* __restrict__ A1p, int s1, int KA,
    const bf16* __restrict__ A2, int s2, int KB,
    const bf16* __restrict__ Bt, int Bts, int Ncols,
    const float* __restrict__ bias,
    void* __restrict__ Cp, int Cstride, int M, int K)
{
  __shared__ short As[128*40];
  __shared__ short Bs[128*40];
  const int tid = threadIdx.x;
  const int row0 = blockIdx.x * 128;
  const int col0 = blockIdx.y * 128;
  const int wave = tid >> 6, lane = tid & 63;
  const int wr = (wave >> 1) * 64, wc = (wave & 1) * 64;
  const int m16 = lane & 15, q = lane >> 4;
  f32x4 acc[4][4] = {};

  for (int k0 = 0; k0 < K; k0 += 32){
    #pragma unroll
    for (int rep = 0; rep < 2; rep++){
      int idx = rep*256 + tid;
      int r = idx >> 2, kc = (idx & 3) * 8;
      int kg = k0 + kc;
      // A chunk
      uint4 va; va.x = va.y = va.z = va.w = 0u;
      int grow = row0 + r;
      if (grow < M){
        if (kg < KA){
          if (AF32){
            const float* ap = (const float*)A1p + grow*s1 + kg;
            float4 f0 = *(const float4*)ap;
            float4 f1 = *(const float4*)(ap + 4);
            va.x = pk(f0.x, f0.y); va.y = pk(f0.z, f0.w);
            va.z = pk(f1.x, f1.y); va.w = pk(f1.z, f1.w);
          } else {
            va = *(const uint4*)((const bf16*)A1p + grow*s1 + kg);
          }
        } else if (kg - KA < KB){
          va = *(const uint4*)(A2 + grow*s2 + (kg - KA));
        }
      }
      *(uint4*)(&As[r*40 + kc]) = va;
      // B chunk
      uint4 vb; vb.x = vb.y = vb.z = vb.w = 0u;
      int gcol = col0 + r;
      if (gcol < Ncols) vb = *(const uint4*)(Bt + gcol*Bts + kg);
      *(uint4*)(&Bs[r*40 + kc]) = vb;
    }
    __syncthreads();
    bf16x8 af[4], bfv[4];
    #pragma unroll
    for (int t = 0; t < 4; t++){
      af[t]  = *(const bf16x8*)(&As[(wr + t*16 + m16)*40 + q*8]);
      bfv[t] = *(const bf16x8*)(&Bs[(wc + t*16 + m16)*40 + q*8]);
    }
    #pragma unroll
    for (int rt = 0; rt < 4; rt++)
      #pragma unroll
      for (int ct = 0; ct < 4; ct++)
        acc[rt][ct] = __builtin_amdgcn_mfma_f32_16x16x32_bf16(af[rt], bfv[ct], acc[rt][ct], 0, 0, 0);
    __syncthreads();
  }

  #pragma unroll
  for (int rt = 0; rt < 4; rt++){
    #pragma unroll
    for (int rr = 0; rr < 4; rr++){
      int row = row0 + wr + rt*16 + q*4 + rr;
      if (row >= M) continue;
      #pragma unroll
      for (int ct = 0; ct < 4; ct++){
        int col = col0 + wc + ct*16 + m16;
        if (col >= Ncols) continue;
        float v = acc[rt][ct][rr] + (bias ? bias[col] : 0.f);
        if (F32OUT) ((float*)Cp)[row*Cstride + col] = v;
        else        ((bf16*)Cp)[row*Cstride + col] = f2b(v);
      }
    }
  }
}

// ------------------------------------------------------------------ aggregation
// one wave per node; lane<40 handles feature pair (2*lane, 2*lane+1)
__global__ __launch_bounds__(256) void k_agg(const bf16* __restrict__ U,
                      const int* __restrict__ rowptr,
                      const int* __restrict__ colidx, bf16* __restrict__ agg)
{
  int n = blockIdx.x*4 + (threadIdx.x >> 6);
  int lane = threadIdx.x & 63;
  if (n >= NN) return;
  int rs = rowptr[n], re = rowptr[n+1];
  int deg = re - rs;
  bool act = lane < 40;
  int fo = lane*2;
  float a0 = 0.f, a1 = 0.f;
  if (act){
    unsigned ua = *(const unsigned*)(U + n*240 + fo);
    a0 = __uint_as_float(ua << 16);
    a1 = __uint_as_float(ua & 0xffff0000u);
  }
  float sb0=0.f, sb1=0.f, sq0=0.f, sq1=0.f;
  float mn0=1e30f, mn1=1e30f, mx0=-1e30f, mx1=-1e30f;
  for (int e = rs; e < re; e++){
    int s = colidx[e];
    if (act){
      unsigned u = *(const unsigned*)(U + s*240 + 80 + fo);
      float b0 = __uint_as_float(u << 16);
      float b1 = __uint_as_float(u & 0xffff0000u);
      sb0 += b0; sq0 += b0*b0; mn0 = fminf(mn0,b0); mx0 = fmaxf(mx0,b0);
      sb1 += b1; sq1 += b1*b1; mn1 = fminf(mn1,b1); mx1 = fmaxf(mx1,b1);
    }
  }
  if (!act) return;
  float degc = (float)(deg > 0 ? deg : 1);
  float inv = 1.f/degc;
  float dm = (float)deg;
  float mean0 = (dm*a0 + sb0)*inv;
  float mean1 = (dm*a1 + sb1)*inv;
  float v0 = (dm*a0*a0 + 2.f*a0*sb0 + sq0)*inv - mean0*mean0;
  float v1 = (dm*a1*a1 + 2.f*a1*sb1 + sq1)*inv - mean1*mean1;
  float sd0 = sqrtf(fmaxf(v0,0.f)+1e-5f);
  float sd1 = sqrtf(fmaxf(v1,0.f)+1e-5f);
  float lo0 = deg>0 ? a0+mn0 : 0.f;
  float lo1 = deg>0 ? a1+mn1 : 0.f;
  float hi0 = deg>0 ? a0+mx0 : 0.f;
  float hi1 = deg>0 ? a1+mx1 : 0.f;
  unsigned* ag = (unsigned*)(agg + n*320 + fo);
  ag[0]   = pk(mean0, mean1);
  ag[40]  = pk(lo0, lo1);
  ag[80]  = pk(hi0, hi1);
  ag[120] = pk(sd0, sd1);
}

// h += relu(P + sc*Q + inv*R + bias2)
__global__ void k_combine(const bf16* __restrict__ U, const float* __restrict__ b2v,
                          const float* __restrict__ scf, const float* __restrict__ invf,
                          float* __restrict__ h){
  int gid = blockIdx.x*256 + threadIdx.x;
  if (gid >= NN*FD) return;
  int n = gid / FD, f = gid - n*FD;
  const bf16* xr = U + n*240;
  float o = b2f(xr[f]) + scf[n]*b2f(xr[80 + f]) + invf[n]*b2f(xr[160 + f]) + b2v[f];
  h[gid] += fmaxf(o, 0.f);
}

// ------------------------------------------------------------------ pooling + head
__global__ void k_pool(const float* __restrict__ h, const int* __restrict__ batch,
                       float* __restrict__ gsum, float* __restrict__ gcnt){
  int gid = blockIdx.x*256 + threadIdx.x;
  if (gid >= NN*FD) return;
  int n = gid / FD, f = gid - n*FD;
  int g = batch[n];
  atomicAdd(&gsum[g*FD + f], h[gid]);
  if (f == 0) atomicAdd(&gcnt[g], 1.f);
}

__global__ void k_mlp(const float* __restrict__ gsum, const float* __restrict__ gcnt,
                      const void* __restrict__ mlpW, const void* __restrict__ mlpb,
                      const int* __restrict__ flag, void* __restrict__ outp){
  int fl = flag[0];
  int g = blockIdx.x*256 + threadIdx.x;
  if (g >= NGR) return;
  float cnt = fmaxf(gcnt[g], 1.f);
  float s = 0.f;
  for (int f = 0; f < FD; f++) s += gsum[g*FD + f] * rdw(mlpW, f, fl);
  float r = s / cnt + rdw(mlpb, 0, fl);
  if (fl) ((float*)outp)[g] = r;
  else    ((bf16*)outp)[g] = f2b(r);
}

// ------------------------------------------------------------------ launch
extern "C" void kernel_launch(void* const* d_in, const int* in_sizes, int n_in,
                              void* d_out, int out_size, void* d_ws, size_t ws_size,
                              hipStream_t stream)
{
  const int*  x     = (const int*) d_in[0];
  const int*  ei    = (const int*) d_in[1];
  const int*  batch = (const int*) d_in[2];
  const void* avgp  = d_in[3];
  const void* aemb  = d_in[4];
  const void* preW  = d_in[5];
  const void* preb  = d_in[6];
  const void* postW = d_in[7];
  const void* postb = d_in[8];
  const void* linW  = d_in[9];
  const void* linb  = d_in[10];
  const void* bng   = d_in[11];
  const void* bnb   = d_in[12];
  const void* bnm   = d_in[13];
  const void* bnv   = d_in[14];
  const void* mlpW  = d_in[15];
  const void* mlpb  = d_in[16];

  char* w = (char*)d_ws;
  int*   deg    = (int*)  (w + 0);            //   200,000
  int*   cursor = (int*)  (w + 200000);       //   200,000
  float* gsum   = (float*)(w + 400000);       //   327,680
  float* gcnt   = (float*)(w + 727680);       //     4,096
  int*   flag   = (int*)  (w + 731776);       //       256   (zero first 732,032 B)
  int*   rowptr = (int*)  (w + 732032);       //   200,064
  int*   colidx = (int*)  (w + 932096);       // 3,200,000
  float* scf    = (float*)(w + 4132096);      //   200,000
  float* invf   = (float*)(w + 4332096);      //   200,000
  float* bias1  = (float*)(w + 4532096);      //     2,560
  float* bias2  = (float*)(w + 4534656);      //     1,280
  bf16*  Btl    = (bf16*) (w + 4535936);      //    61,440
  bf16*  Bt1    = (bf16*) (w + 4597376);      //   122,880
  bf16*  Bt2    = (bf16*) (w + 4720256);      //   798,720
  float* h      = (float*)(w + 5518976);      // 16,000,000  f32 [N,80]
  bf16*  U      = (bf16*) (w + 21518976);     // 24,000,000  bf16 [N,240] ab then PQR
  bf16*  agg    = (bf16*) (w + 45518976);     // 32,000,000  bf16 [N,320]
  // pwb/Wf overlaid in agg region: read completes before first k_agg write (stream-ordered)
  bf16*  pwb    = (bf16*) (w + 45518976);     //   665,600
  float* Wf     = (float*)(w + 46184576);     // 1,331,200
  // total 77,518,976 B

  k_zero <<<(183008 + 255)/256, 256, 0, stream>>>((int*)w, 183008);
  k_probe<<<(9*119*80 + 255)/256, 256, 0, stream>>>(aemb, 9*119*80, flag);

  k_cvt_pw   <<<(4*1040*80 + 255)/256, 256, 0, stream>>>(postW, flag, pwb);
  k_prep_lin <<<(4*80*96 + 255)/256, 256, 0, stream>>>(linW, bng, bnv, flag, Btl);
  k_prep_Bt1 <<<(4*160*96 + 255)/256, 256, 0, stream>>>(preW, preb, flag, Bt1, bias1);
  k_prep_bias2<<<2, 256, 0, stream>>>(postb, linW, linb, bng, bnb, bnm, bnv, flag, bias2);

  for (int i = 0; i < 4; i++)
    k_mgemm<0,1><<<dim3(9,1), 256, 0, stream>>>(
        pwb + i*83200, 80, 80, nullptr, 0, 0,
        Btl + i*7680, 96, 80, nullptr, Wf + i*83200, 80, 1040, 96);
  k_prep_Bt2<<<(4*240*416 + 255)/256, 256, 0, stream>>>(Wf, Bt2);

  k_atom   <<<(NN*FD + 255)/256, 256, 0, stream>>>(x, aemb, flag, h);
  k_deg    <<<(NE + 255)/256, 256, 0, stream>>>(ei, deg);
  k_scan   <<<1, 256, 0, stream>>>(deg, rowptr);
  k_scalars<<<(NN + 255)/256, 256, 0, stream>>>(deg, avgp, flag, scf, invf);
  k_scatter<<<(NE + 255)/256, 256, 0, stream>>>(ei, rowptr, cursor, colidx);

  for (int i = 0; i < 4; i++){
    k_mgemm<1,0><<<dim3(391,2), 256, 0, stream>>>(
        h, 80, 80, nullptr, 0, 0,
        Bt1 + i*15360, 96, 160, bias1 + i*160, U, 240, NN, 96);
    k_agg<<<12500, 256, 0, stream>>>(U, rowptr, colidx, agg);
    k_mgemm<1,0><<<dim3(391,2), 256, 0, stream>>>(
        h, 80, 80, agg, 320, 320,
        Bt2 + i*99840, 416, 240, nullptr, U, 240, NN, 416);
    k_combine<<<(NN*FD + 255)/256, 256, 0, stream>>>(U, bias2 + i*80, scf, invf, h);
  }

  k_pool<<<(NN*FD + 255)/256, 256, 0, stream>>>(h, batch, gsum, gcnt);
  k_mlp <<<(NGR + 255)/256, 256, 0, stream>>>(gsum, gcnt, mlpW, mlpb, flag, d_out);
}

// Round 4
// 932.467 us; speedup vs baseline: 1.6519x; 1.2443x over previous
//
#include <hip/hip_runtime.h>
#include <hip/hip_bf16.h>

#define NN 50000
#define NE 800000
#define FD 80
#define NGR 1024
#define NF 9

using bf16 = __hip_bfloat16;
typedef __attribute__((ext_vector_type(8))) short bf16x8;
typedef __attribute__((ext_vector_type(4))) float f32x4;

static __device__ __forceinline__ float b2f(bf16 v){ return __bfloat162float(v); }
static __device__ __forceinline__ bf16 f2b(float v){ return __float2bfloat16(v); }
static __device__ __forceinline__ float rdw(const void* p, int i, int fl){
  return fl ? ((const float*)p)[i] : b2f(((const bf16*)p)[i]);
}
static __device__ __forceinline__ unsigned pk(float a, float b){
  bf16 x = f2b(a), y = f2b(b);
  return (unsigned)*(unsigned short*)&x | ((unsigned)*(unsigned short*)&y << 16);
}

// ------------------------------------------------------------------ utility
__global__ void k_zero(int* __restrict__ p, int n){
  int t = blockIdx.x*256 + threadIdx.x;
  if (t < n) p[t] = 0;
}

__global__ void k_probe(const void* __restrict__ emb, int n, int* __restrict__ flag){
  int t = blockIdx.x*256 + threadIdx.x;
  if (t >= n) return;
  float v = b2f(((const bf16*)emb)[t]);
  if (!(fabsf(v) < 1e4f)) atomicOr(flag, 1);
}

// ------------------------------------------------------------------ weight prep
__global__ void k_cvt_pw(const void* __restrict__ postW, const int* __restrict__ flag,
                         bf16* __restrict__ pwb){
  int fl = flag[0];
  int t = blockIdx.x*256 + threadIdx.x;
  if (t < 4*1040*80) pwb[t] = f2b(rdw(postW, t, fl));
}

// Btl[i][c][j] (96-k): scaled linW^T: linW[j][c]*gs[c], zero pad j>=80
__global__ void k_prep_lin(const void* __restrict__ linW, const void* __restrict__ gamma,
                           const void* __restrict__ var, const int* __restrict__ flag,
                           bf16* __restrict__ Btl){
  int fl = flag[0];
  int t = blockIdx.x*256 + threadIdx.x;
  if (t >= 4*80*96) return;
  int j = t % 96;
  int c = (t/96) % 80;
  int i = t/(96*80);
  float v = 0.f;
  if (j < 80){
    float gs = rdw(gamma, i*80 + c, fl) * rsqrtf(rdw(var, i*80 + c, fl) + 1e-5f);
    v = rdw(linW, i*6400 + j*80 + c, fl) * gs;
  }
  Btl[t] = f2b(v);
}

// Bt1[i][c][k] (c<160 cols, 96-k): col c<80 -> preW[i][k][c], else preW[i][80+k][c-80]
__global__ void k_prep_Bt1(const void* __restrict__ preW, const void* __restrict__ preb,
                           const int* __restrict__ flag,
                           bf16* __restrict__ Bt1, float* __restrict__ bias1){
  int fl = flag[0];
  int t = blockIdx.x*256 + threadIdx.x;
  if (t >= 4*160*96) return;
  int k = t % 96;
  int c = (t/96) % 160;
  int i = t/(96*160);
  float v = 0.f;
  if (k < 80)
    v = (c < 80) ? rdw(preW, (i*160 + k)*80 + c, fl)
                 : rdw(preW, (i*160 + 80 + k)*80 + (c - 80), fl);
  Bt1[t] = f2b(v);
  if (k == 0) bias1[i*160 + c] = (c < 80) ? rdw(preb, i*80 + c, fl) : 0.f;
}

// Bt2[i][c][k] (c<240 cols, 416-k) from Wf (f32 [i][1040][80]).
__global__ void k_prep_Bt2(const float* __restrict__ Wf, bf16* __restrict__ Bt2){
  int t = blockIdx.x*256 + threadIdx.x;
  if (t >= 4*240*416) return;
  int k = t % 416;
  int c = (t/416) % 240;
  int i = t/(416*240);
  float v = 0.f;
  if (k < 400){
    int blk = c/80, f = c - blk*80;
    if (blk == 0) v = Wf[(i*1040 + k)*80 + f];
    else if (k >= 80){
      int row = (blk == 1 ? 400 : 720) + (k - 80);
      v = Wf[(i*1040 + row)*80 + f];
    }
  }
  Bt2[t] = f2b(v);
}

__global__ void k_prep_bias2(const void* __restrict__ postb, const void* __restrict__ linW,
                             const void* __restrict__ linb, const void* __restrict__ gamma,
                             const void* __restrict__ beta, const void* __restrict__ mu,
                             const void* __restrict__ var, const int* __restrict__ flag,
                             float* __restrict__ bias2){
  int fl = flag[0];
  int t = blockIdx.x*256 + threadIdx.x;
  if (t >= 4*80) return;
  int i = t / 80, f = t - i*80;
  float s = 0.f;
  for (int j = 0; j < 80; j++)
    s += rdw(postb, i*80 + j, fl) * rdw(linW, (i*80 + j)*80 + f, fl);
  s += rdw(linb, t, fl);
  float gs = rdw(gamma, t, fl) * rsqrtf(rdw(var, t, fl) + 1e-5f);
  bias2[t] = (s - rdw(mu, t, fl)) * gs + rdw(beta, t, fl);
}

// ------------------------------------------------------------------ graph prep
__global__ void k_atom(const int* __restrict__ x, const void* __restrict__ emb,
                       const int* __restrict__ flag, float* __restrict__ h){
  int fl = flag[0];
  int gid = blockIdx.x*256 + threadIdx.x;
  if (gid >= NN*FD) return;
  int n = gid / FD, f = gid - n*FD;
  float s = 0.f;
  #pragma unroll
  for (int c = 0; c < NF; c++){
    int row = x[n*NF + c];
    s += rdw(emb, (c*119 + row)*FD + f, fl);
  }
  h[gid] = s;
}

__global__ void k_deg(const int* __restrict__ ei, int* __restrict__ deg){
  int e = blockIdx.x*256 + threadIdx.x;
  if (e < NE) atomicAdd(&deg[ei[NE + e]], 1);
}

__global__ __launch_bounds__(256) void k_scan(const int* __restrict__ deg,
                                              int* __restrict__ rowptr){
  __shared__ int csum[256];
  const int CH = (NN + 255)/256;
  int t = threadIdx.x;
  int lo = t*CH, hi = lo + CH; if (hi > NN) hi = NN; if (lo > NN) lo = NN;
  int s = 0;
  for (int i = lo; i < hi; i++) s += deg[i];
  csum[t] = s;
  __syncthreads();
  if (t == 0){
    int run = 0;
    for (int i = 0; i < 256; i++){ int v = csum[i]; csum[i] = run; run += v; }
    rowptr[NN] = run;
  }
  __syncthreads();
  int run = csum[t];
  for (int i = lo; i < hi; i++){ rowptr[i] = run; run += deg[i]; }
}

__global__ void k_scalars(const int* __restrict__ deg, const void* __restrict__ avgp,
                          const int* __restrict__ flag,
                          float* __restrict__ scf, float* __restrict__ invf){
  int fl = flag[0];
  int n = blockIdx.x*256 + threadIdx.x;
  if (n >= NN) return;
  int d = deg[n];
  float degc = (float)(d > 0 ? d : 1);
  float logd = logf(degc + 1.f);
  float avg = rdw(avgp, 0, fl);
  scf[n] = logd / avg;
  invf[n] = avg / logd;
}

__global__ void k_scatter(const int* __restrict__ ei, const int* __restrict__ rowptr,
                          int* __restrict__ cursor, int* __restrict__ colidx){
  int e = blockIdx.x*256 + threadIdx.x;
  if (e >= NE) return;
  int d = ei[NE + e];
  int pos = rowptr[d] + atomicAdd(&cursor[d], 1);
  colidx[pos] = ei[e];
}

// ------------------------------------------------------------------ MFMA GEMM
// OUTMODE: 0 = bf16 single buffer (stride Cstride), 1 = f32 single, 2 = split bf16:
//          col<80 -> C1[row*80+col], 80<=col<160 -> C2[row*80+col-80].
template<int AF32, int OUTMODE>
__global__ __launch_bounds__(256) void k_mgemm(
    const void* __restrict__ A1p, int s1, int KA,
    const bf16* __restrict__ A2, int s2, int KB,
    const bf16* __restrict__ Bt, int Bts, int Ncols,
    const float* __restrict__ bias,
    void* __restrict__ Cp, void* __restrict__ Cp2, int Cstride, int M, int K)
{
  __shared__ short As[128*40];
  __shared__ short Bs[128*40];
  const int tid = threadIdx.x;
  const int row0 = blockIdx.x * 128;
  const int col0 = blockIdx.y * 128;
  const int wave = tid >> 6, lane = tid & 63;
  const int wr = (wave >> 1) * 64, wc = (wave & 1) * 64;
  const int m16 = lane & 15, q = lane >> 4;
  f32x4 acc[4][4] = {};

  for (int k0 = 0; k0 < K; k0 += 32){
    #pragma unroll
    for (int rep = 0; rep < 2; rep++){
      int idx = rep*256 + tid;
      int r = idx >> 2, kc = (idx & 3) * 8;
      int kg = k0 + kc;
      uint4 va; va.x = va.y = va.z = va.w = 0u;
      int grow = row0 + r;
      if (grow < M){
        if (kg < KA){
          if (AF32){
            const float* ap = (const float*)A1p + grow*s1 + kg;
            float4 f0 = *(const float4*)ap;
            float4 f1 = *(const float4*)(ap + 4);
            va.x = pk(f0.x, f0.y); va.y = pk(f0.z, f0.w);
            va.z = pk(f1.x, f1.y); va.w = pk(f1.z, f1.w);
          } else {
            va = *(const uint4*)((const bf16*)A1p + grow*s1 + kg);
          }
        } else if (kg - KA < KB){
          va = *(const uint4*)(A2 + grow*s2 + (kg - KA));
        }
      }
      *(uint4*)(&As[r*40 + kc]) = va;
      uint4 vb; vb.x = vb.y = vb.z = vb.w = 0u;
      int gcol = col0 + r;
      if (gcol < Ncols) vb = *(const uint4*)(Bt + gcol*Bts + kg);
      *(uint4*)(&Bs[r*40 + kc]) = vb;
    }
    __syncthreads();
    bf16x8 af[4], bfv[4];
    #pragma unroll
    for (int t = 0; t < 4; t++){
      af[t]  = *(const bf16x8*)(&As[(wr + t*16 + m16)*40 + q*8]);
      bfv[t] = *(const bf16x8*)(&Bs[(wc + t*16 + m16)*40 + q*8]);
    }
    #pragma unroll
    for (int rt = 0; rt < 4; rt++)
      #pragma unroll
      for (int ct = 0; ct < 4; ct++)
        acc[rt][ct] = __builtin_amdgcn_mfma_f32_16x16x32_bf16(af[rt], bfv[ct], acc[rt][ct], 0, 0, 0);
    __syncthreads();
  }

  #pragma unroll
  for (int rt = 0; rt < 4; rt++){
    #pragma unroll
    for (int rr = 0; rr < 4; rr++){
      int row = row0 + wr + rt*16 + q*4 + rr;
      if (row >= M) continue;
      #pragma unroll
      for (int ct = 0; ct < 4; ct++){
        int col = col0 + wc + ct*16 + m16;
        if (col >= Ncols) continue;
        float v = acc[rt][ct][rr] + (bias ? bias[col] : 0.f);
        if (OUTMODE == 1)      ((float*)Cp)[row*Cstride + col] = v;
        else if (OUTMODE == 0) ((bf16*)Cp)[row*Cstride + col] = f2b(v);
        else {
          if (col < 80) ((bf16*)Cp )[row*80 + col]      = f2b(v);
          else          ((bf16*)Cp2)[row*80 + col - 80] = f2b(v);
        }
      }
    }
  }
}

// ------------------------------------------------------------------ aggregation
// one wave per node; lane<40 handles feature pair (2*lane, 2*lane+1); edge loop unrolled x4
__global__ __launch_bounds__(256) void k_agg(const bf16* __restrict__ Ua,
                      const bf16* __restrict__ Ub,
                      const int* __restrict__ rowptr,
                      const int* __restrict__ colidx, bf16* __restrict__ agg)
{
  int n = blockIdx.x*4 + (threadIdx.x >> 6);
  int lane = threadIdx.x & 63;
  if (n >= NN) return;
  int rs = rowptr[n], re = rowptr[n+1];
  int deg = re - rs;
  bool act = lane < 40;
  int fo = lane*2;
  float a0 = 0.f, a1 = 0.f;
  if (act){
    unsigned ua = *(const unsigned*)(Ua + n*80 + fo);
    a0 = __uint_as_float(ua << 16);
    a1 = __uint_as_float(ua & 0xffff0000u);
  }
  float sb0=0.f, sb1=0.f, sq0=0.f, sq1=0.f;
  float mn0=1e30f, mn1=1e30f, mx0=-1e30f, mx1=-1e30f;

#define ACC(u) { \
    float b0 = __uint_as_float((u) << 16); \
    float b1 = __uint_as_float((u) & 0xffff0000u); \
    sb0 += b0; sq0 += b0*b0; mn0 = fminf(mn0,b0); mx0 = fmaxf(mx0,b0); \
    sb1 += b1; sq1 += b1*b1; mn1 = fminf(mn1,b1); mx1 = fmaxf(mx1,b1); }

  int e = rs;
  for (; e + 4 <= re; e += 4){
    int s0 = colidx[e], s1 = colidx[e+1], s2 = colidx[e+2], s3 = colidx[e+3];
    unsigned u0=0u, u1=0u, u2=0u, u3=0u;
    if (act){
      u0 = *(const unsigned*)(Ub + s0*80 + fo);
      u1 = *(const unsigned*)(Ub + s1*80 + fo);
      u2 = *(const unsigned*)(Ub + s2*80 + fo);
      u3 = *(const unsigned*)(Ub + s3*80 + fo);
    }
    ACC(u0); ACC(u1); ACC(u2); ACC(u3);
  }
  for (; e < re; e++){
    int s = colidx[e];
    unsigned u = 0u;
    if (act) u = *(const unsigned*)(Ub + s*80 + fo);
    ACC(u);
  }
#undef ACC

  if (!act) return;
  float degc = (float)(deg > 0 ? deg : 1);
  float inv = 1.f/degc;
  float dm = (float)deg;
  float mean0 = (dm*a0 + sb0)*inv;
  float mean1 = (dm*a1 + sb1)*inv;
  float v0 = (dm*a0*a0 + 2.f*a0*sb0 + sq0)*inv - mean0*mean0;
  float v1 = (dm*a1*a1 + 2.f*a1*sb1 + sq1)*inv - mean1*mean1;
  float sd0 = sqrtf(fmaxf(v0,0.f)+1e-5f);
  float sd1 = sqrtf(fmaxf(v1,0.f)+1e-5f);
  float lo0 = deg>0 ? a0+mn0 : 0.f;
  float lo1 = deg>0 ? a1+mn1 : 0.f;
  float hi0 = deg>0 ? a0+mx0 : 0.f;
  float hi1 = deg>0 ? a1+mx1 : 0.f;
  unsigned* ag = (unsigned*)(agg + n*320 + fo);
  ag[0]   = pk(mean0, mean1);
  ag[40]  = pk(lo0, lo1);
  ag[80]  = pk(hi0, hi1);
  ag[120] = pk(sd0, sd1);
}

// h += relu(P + sc*Q + inv*R + bias2)   (U stride 240: P|Q|R)
__global__ void k_combine(const bf16* __restrict__ U, const float* __restrict__ b2v,
                          const float* __restrict__ scf, const float* __restrict__ invf,
                          float* __restrict__ h){
  int gid = blockIdx.x*256 + threadIdx.x;
  if (gid >= NN*FD) return;
  int n = gid / FD, f = gid - n*FD;
  const bf16* xr = U + n*240;
  float o = b2f(xr[f]) + scf[n]*b2f(xr[80 + f]) + invf[n]*b2f(xr[160 + f]) + b2v[f];
  h[gid] += fmaxf(o, 0.f);
}

// ------------------------------------------------------------------ fused mean-pool + head
// one block per graph; batch[] is sorted -> binary-search the node range
__global__ __launch_bounds__(128) void k_poolmlp(const float* __restrict__ h,
                        const int* __restrict__ batch,
                        const void* __restrict__ mlpW, const void* __restrict__ mlpb,
                        const int* __restrict__ flag, void* __restrict__ outp){
  __shared__ float sred[128];
  __shared__ int sb[2];
  int g = blockIdx.x;
  int t = threadIdx.x;
  if (t < 2){
    int target = g + t;
    int lo = 0, hi = NN;
    while (lo < hi){ int mid = (lo + hi) >> 1; if (batch[mid] < target) lo = mid + 1; else hi = mid; }
    sb[t] = lo;
  }
  __syncthreads();
  int lo = sb[0], hi = sb[1];
  float s = 0.f;
  if (t < 80)
    for (int n = lo; n < hi; n++) s += h[n*80 + t];
  int fl = flag[0];
  float wv = (t < 80) ? rdw(mlpW, t, fl) : 0.f;
  sred[t] = s * wv;
  __syncthreads();
  for (int off = 64; off > 0; off >>= 1){
    if (t < off) sred[t] += sred[t + off];
    __syncthreads();
  }
  if (t == 0){
    float cnt = (float)(hi - lo); if (cnt < 1.f) cnt = 1.f;
    float r = sred[0]/cnt + rdw(mlpb, 0, fl);
    if (fl) ((float*)outp)[g] = r;
    else    ((bf16*)outp)[g] = f2b(r);
  }
}

// ------------------------------------------------------------------ launch
extern "C" void kernel_launch(void* const* d_in, const int* in_sizes, int n_in,
                              void* d_out, int out_size, void* d_ws, size_t ws_size,
                              hipStream_t stream)
{
  const int*  x     = (const int*) d_in[0];
  const int*  ei    = (const int*) d_in[1];
  const int*  batch = (const int*) d_in[2];
  const void* avgp  = d_in[3];
  const void* aemb  = d_in[4];
  const void* preW  = d_in[5];
  const void* preb  = d_in[6];
  const void* postW = d_in[7];
  const void* postb = d_in[8];
  const void* linW  = d_in[9];
  const void* linb  = d_in[10];
  const void* bng   = d_in[11];
  const void* bnb   = d_in[12];
  const void* bnm   = d_in[13];
  const void* bnv   = d_in[14];
  const void* mlpW  = d_in[15];
  const void* mlpb  = d_in[16];

  char* w = (char*)d_ws;
  int*   deg    = (int*)  (w + 0);            //   200,000  (zeroed)
  int*   cursor = (int*)  (w + 200000);       //   200,000  (zeroed)
  int*   flag   = (int*)  (w + 400000);       //       256  (zeroed: 400,256 B total)
  int*   rowptr = (int*)  (w + 400256);       //   200,064
  int*   colidx = (int*)  (w + 600320);       // 3,200,000
  float* scf    = (float*)(w + 3800320);      //   200,000
  float* invf   = (float*)(w + 4000320);      //   200,000
  float* bias1  = (float*)(w + 4200320);      //     2,560
  float* bias2  = (float*)(w + 4202880);      //     1,280
  bf16*  Btl    = (bf16*) (w + 4204160);      //    61,440
  bf16*  Bt1    = (bf16*) (w + 4265600);      //   122,880
  bf16*  Bt2    = (bf16*) (w + 4388480);      //   798,720
  float* h      = (float*)(w + 5187200);      // 16,000,000  f32 [N,80]
  bf16*  Ua     = (bf16*) (w + 21187200);     //  8,000,000  bf16 [N,80] (a)
  bf16*  Ub     = (bf16*) (w + 29187200);     //  8,000,000  bf16 [N,80] (b)
  bf16*  U240   = (bf16*) (w + 21187200);     // 24,000,000  bf16 [N,240] PQR (overlays Ua/Ub)
  bf16*  agg    = (bf16*) (w + 45187200);     // 32,000,000  bf16 [N,320]
  bf16*  pwb    = (bf16*) (w + 45187200);     //   665,600   (overlay in agg, used pre-loop)
  float* Wf     = (float*)(w + 45852800);     // 1,331,200   (overlay in agg)
  // total 77,187,200 B

  k_zero <<<(100064 + 255)/256, 256, 0, stream>>>((int*)w, 100064);
  k_probe<<<(9*119*80 + 255)/256, 256, 0, stream>>>(aemb, 9*119*80, flag);

  k_cvt_pw   <<<(4*1040*80 + 255)/256, 256, 0, stream>>>(postW, flag, pwb);
  k_prep_lin <<<(4*80*96 + 255)/256, 256, 0, stream>>>(linW, bng, bnv, flag, Btl);
  k_prep_Bt1 <<<(4*160*96 + 255)/256, 256, 0, stream>>>(preW, preb, flag, Bt1, bias1);
  k_prep_bias2<<<2, 256, 0, stream>>>(postb, linW, linb, bng, bnb, bnm, bnv, flag, bias2);

  for (int i = 0; i < 4; i++)
    k_mgemm<0,1><<<dim3(9,1), 256, 0, stream>>>(
        pwb + i*83200, 80, 80, nullptr, 0, 0,
        Btl + i*7680, 96, 80, nullptr, Wf + i*83200, nullptr, 80, 1040, 96);
  k_prep_Bt2<<<(4*240*416 + 255)/256, 256, 0, stream>>>(Wf, Bt2);

  k_atom   <<<(NN*FD + 255)/256, 256, 0, stream>>>(x, aemb, flag, h);
  k_deg    <<<(NE + 255)/256, 256, 0, stream>>>(ei, deg);
  k_scan   <<<1, 256, 0, stream>>>(deg, rowptr);
  k_scalars<<<(NN + 255)/256, 256, 0, stream>>>(deg, avgp, flag, scf, invf);
  k_scatter<<<(NE + 255)/256, 256, 0, stream>>>(ei, rowptr, cursor, colidx);

  for (int i = 0; i < 4; i++){
    k_mgemm<1,2><<<dim3(391,2), 256, 0, stream>>>(
        h, 80, 80, nullptr, 0, 0,
        Bt1 + i*15360, 96, 160, bias1 + i*160, Ua, Ub, 0, NN, 96);
    k_agg<<<12500, 256, 0, stream>>>(Ua, Ub, rowptr, colidx, agg);
    k_mgemm<1,0><<<dim3(391,2), 256, 0, stream>>>(
        h, 80, 80, agg, 320, 320,
        Bt2 + i*99840, 416, 240, nullptr, U240, nullptr, 240, NN, 416);
    k_combine<<<(NN*FD + 255)/256, 256, 0, stream>>>(U240, bias2 + i*80, scf, invf, h);
  }

  k_poolmlp<<<NGR, 128, 0, stream>>>(h, batch, mlpW, mlpb, flag, d_out);
}

// Round 5
// 772.489 us; speedup vs baseline: 1.9940x; 1.2071x over previous
//
#include <hip/hip_runtime.h>
#include <hip/hip_bf16.h>

#define NN 50000
#define NE 800000
#define FD 80
#define NGR 1024
#define NF 9

using bf16 = __hip_bfloat16;
typedef __attribute__((ext_vector_type(8))) short bf16x8;
typedef __attribute__((ext_vector_type(4))) float f32x4;

static __device__ __forceinline__ float b2f(bf16 v){ return __bfloat162float(v); }
static __device__ __forceinline__ bf16 f2b(float v){ return __float2bfloat16(v); }
static __device__ __forceinline__ float rdw(const void* p, int i, int fl){
  return fl ? ((const float*)p)[i] : b2f(((const bf16*)p)[i]);
}
static __device__ __forceinline__ unsigned pk(float a, float b){
  bf16 x = f2b(a), y = f2b(b);
  return (unsigned)*(unsigned short*)&x | ((unsigned)*(unsigned short*)&y << 16);
}

// ------------------------------------------------------------------ utility
__global__ void k_zero(int* __restrict__ p, int n){
  int t = blockIdx.x*256 + threadIdx.x;
  if (t < n) p[t] = 0;
}

// sample-based dtype probe: 4096 elements is statistically certain
__global__ void k_probe(const void* __restrict__ emb, int* __restrict__ flag){
  int t = blockIdx.x*256 + threadIdx.x;
  float v = b2f(((const bf16*)emb)[t]);
  if (!(fabsf(v) < 1e4f)) atomicOr(flag, 1);
}

// ------------------------------------------------------------------ fused weight prep
// blocks [0,1300): cvt_pw; [1300,1420): prep_lin; [1420,1660): prep_Bt1; [1660,1662): prep_bias2
__global__ __launch_bounds__(256) void k_prep_all(
    const void* __restrict__ preW, const void* __restrict__ preb,
    const void* __restrict__ postW, const void* __restrict__ postb,
    const void* __restrict__ linW, const void* __restrict__ linb,
    const void* __restrict__ bng, const void* __restrict__ bnb,
    const void* __restrict__ bnm, const void* __restrict__ bnv,
    const int* __restrict__ flag,
    bf16* __restrict__ pwb, bf16* __restrict__ Btl, bf16* __restrict__ Bt1,
    float* __restrict__ bias1, float* __restrict__ bias2)
{
  int fl = flag[0];
  int b = blockIdx.x;
  if (b < 1300){                                   // postW -> bf16
    int t = b*256 + threadIdx.x;                   // < 332,800 exactly
    pwb[t] = f2b(rdw(postW, t, fl));
  } else if (b < 1420){                            // Btl[i][c][j]: linW[j][c]*gs[c]
    int t = (b - 1300)*256 + threadIdx.x;
    int j = t % 96, c = (t/96) % 80, i = t/(96*80);
    float v = 0.f;
    if (j < 80){
      float gs = rdw(bng, i*80 + c, fl) * rsqrtf(rdw(bnv, i*80 + c, fl) + 1e-5f);
      v = rdw(linW, i*6400 + j*80 + c, fl) * gs;
    }
    Btl[t] = f2b(v);
  } else if (b < 1660){                            // Bt1 + bias1
    int t = (b - 1420)*256 + threadIdx.x;
    int k = t % 96, c = (t/96) % 160, i = t/(96*160);
    float v = 0.f;
    if (k < 80)
      v = (c < 80) ? rdw(preW, (i*160 + k)*80 + c, fl)
                   : rdw(preW, (i*160 + 80 + k)*80 + (c - 80), fl);
    Bt1[t] = f2b(v);
    if (k == 0) bias1[i*160 + c] = (c < 80) ? rdw(preb, i*80 + c, fl) : 0.f;
  } else {                                         // bias2
    int t = (b - 1660)*256 + threadIdx.x;
    if (t >= 4*80) return;
    int i = t / 80, f = t - i*80;
    float s = 0.f;
    for (int j = 0; j < 80; j++)
      s += rdw(postb, i*80 + j, fl) * rdw(linW, (i*80 + j)*80 + f, fl);
    s += rdw(linb, t, fl);
    float gs = rdw(bng, t, fl) * rsqrtf(rdw(bnv, t, fl) + 1e-5f);
    bias2[t] = (s - rdw(bnm, t, fl)) * gs + rdw(bnb, t, fl);
  }
}

// Bt2[i][c][k] (c<240 cols, 416-k) from Wf (f32 [i][1040][80]).
__global__ void k_prep_Bt2(const float* __restrict__ Wf, bf16* __restrict__ Bt2){
  int t = blockIdx.x*256 + threadIdx.x;
  if (t >= 4*240*416) return;
  int k = t % 416;
  int c = (t/416) % 240;
  int i = t/(416*240);
  float v = 0.f;
  if (k < 400){
    int blk = c/80, f = c - blk*80;
    if (blk == 0) v = Wf[(i*1040 + k)*80 + f];
    else if (k >= 80){
      int row = (blk == 1 ? 400 : 720) + (k - 80);
      v = Wf[(i*1040 + row)*80 + f];
    }
  }
  Bt2[t] = f2b(v);
}

// ------------------------------------------------------------------ graph prep
__global__ void k_atom(const int* __restrict__ x, const void* __restrict__ emb,
                       const int* __restrict__ flag, float* __restrict__ h){
  int fl = flag[0];
  int gid = blockIdx.x*256 + threadIdx.x;
  if (gid >= NN*FD) return;
  int n = gid / FD, f = gid - n*FD;
  float s = 0.f;
  #pragma unroll
  for (int c = 0; c < NF; c++){
    int row = x[n*NF + c];
    s += rdw(emb, (c*119 + row)*FD + f, fl);
  }
  h[gid] = s;
}

__global__ void k_deg(const int* __restrict__ ei, int* __restrict__ deg){
  int e = blockIdx.x*256 + threadIdx.x;
  if (e < NE) atomicAdd(&deg[ei[NE + e]], 1);
}

// ---- 3-phase scan: (1) per-block sums, (2) scan of 196 block sums, (3) per-block scan + scalars
__global__ __launch_bounds__(256) void k_scan1(const int* __restrict__ deg, int* __restrict__ bsum){
  __shared__ int buf[256];
  int idx = blockIdx.x*256 + threadIdx.x;
  buf[threadIdx.x] = (idx < NN) ? deg[idx] : 0;
  __syncthreads();
  for (int off = 128; off > 0; off >>= 1){
    if (threadIdx.x < off) buf[threadIdx.x] += buf[threadIdx.x + off];
    __syncthreads();
  }
  if (threadIdx.x == 0) bsum[blockIdx.x] = buf[0];
}

__global__ __launch_bounds__(256) void k_scan2(int* __restrict__ bsum, int* __restrict__ rowptr){
  __shared__ int buf[256];
  int t = threadIdx.x;
  int v = (t < 196) ? bsum[t] : 0;
  buf[t] = v;
  __syncthreads();
  for (int off = 1; off < 256; off <<= 1){
    int xv = (t >= off) ? buf[t - off] : 0;
    __syncthreads();
    buf[t] += xv;
    __syncthreads();
  }
  if (t < 196) bsum[t] = buf[t] - v;     // exclusive
  if (t == 255) rowptr[NN] = buf[255];   // == NE
}

__global__ __launch_bounds__(256) void k_scan3(const int* __restrict__ deg,
                        const int* __restrict__ bsum, const void* __restrict__ avgp,
                        const int* __restrict__ flag, int* __restrict__ rowptr,
                        float* __restrict__ scf, float* __restrict__ invf){
  __shared__ int buf[256];
  int t = threadIdx.x;
  int idx = blockIdx.x*256 + t;
  int v = (idx < NN) ? deg[idx] : 0;
  buf[t] = v;
  __syncthreads();
  for (int off = 1; off < 256; off <<= 1){
    int xv = (t >= off) ? buf[t - off] : 0;
    __syncthreads();
    buf[t] += xv;
    __syncthreads();
  }
  if (idx < NN){
    rowptr[idx] = bsum[blockIdx.x] + buf[t] - v;
    float degc = (float)(v > 0 ? v : 1);
    float logd = logf(degc + 1.f);
    float avg = rdw(avgp, 0, flag[0]);
    scf[idx] = logd / avg;
    invf[idx] = avg / logd;
  }
}

__global__ void k_scatter(const int* __restrict__ ei, const int* __restrict__ rowptr,
                          int* __restrict__ cursor, int* __restrict__ colidx){
  int e = blockIdx.x*256 + threadIdx.x;
  if (e >= NE) return;
  int d = ei[NE + e];
  int pos = rowptr[d] + atomicAdd(&cursor[d], 1);
  colidx[pos] = ei[e];
}

// ------------------------------------------------------------------ MFMA GEMM
// OUTMODE: 0 = bf16 single buffer (stride Cstride), 1 = f32 single, 2 = split bf16.
// blockIdx.z selects layer via byte strides lA1b/lBtb/lCb (0 for single-layer calls).
template<int AF32, int OUTMODE>
__global__ __launch_bounds__(256) void k_mgemm(
    const void* __restrict__ A1p, int s1, int KA,
    const bf16* __restrict__ A2, int s2, int KB,
    const bf16* __restrict__ Btp, int Bts, int Ncols,
    const float* __restrict__ bias,
    void* __restrict__ Cbase, void* __restrict__ Cp2, int Cstride, int M, int K,
    int lA1b, int lBtb, int lCb)
{
  const void* A1 = (const char*)A1p + (size_t)blockIdx.z*lA1b;
  const bf16* Bt = (const bf16*)((const char*)Btp + (size_t)blockIdx.z*lBtb);
  void* Cp = (char*)Cbase + (size_t)blockIdx.z*lCb;

  __shared__ short As[128*40];
  __shared__ short Bs[128*40];
  const int tid = threadIdx.x;
  const int row0 = blockIdx.x * 128;
  const int col0 = blockIdx.y * 128;
  const int wave = tid >> 6, lane = tid & 63;
  const int wr = (wave >> 1) * 64, wc = (wave & 1) * 64;
  const int m16 = lane & 15, q = lane >> 4;
  f32x4 acc[4][4] = {};

  for (int k0 = 0; k0 < K; k0 += 32){
    #pragma unroll
    for (int rep = 0; rep < 2; rep++){
      int idx = rep*256 + tid;
      int r = idx >> 2, kc = (idx & 3) * 8;
      int kg = k0 + kc;
      uint4 va; va.x = va.y = va.z = va.w = 0u;
      int grow = row0 + r;
      if (grow < M){
        if (kg < KA){
          if (AF32){
            const float* ap = (const float*)A1 + grow*s1 + kg;
            float4 f0 = *(const float4*)ap;
            float4 f1 = *(const float4*)(ap + 4);
            va.x = pk(f0.x, f0.y); va.y = pk(f0.z, f0.w);
            va.z = pk(f1.x, f1.y); va.w = pk(f1.z, f1.w);
          } else {
            va = *(const uint4*)((const bf16*)A1 + grow*s1 + kg);
          }
        } else if (kg - KA < KB){
          va = *(const uint4*)(A2 + grow*s2 + (kg - KA));
        }
      }
      *(uint4*)(&As[r*40 + kc]) = va;
      uint4 vb; vb.x = vb.y = vb.z = vb.w = 0u;
      int gcol = col0 + r;
      if (gcol < Ncols) vb = *(const uint4*)(Bt + gcol*Bts + kg);
      *(uint4*)(&Bs[r*40 + kc]) = vb;
    }
    __syncthreads();
    bf16x8 af[4], bfv[4];
    #pragma unroll
    for (int t = 0; t < 4; t++){
      af[t]  = *(const bf16x8*)(&As[(wr + t*16 + m16)*40 + q*8]);
      bfv[t] = *(const bf16x8*)(&Bs[(wc + t*16 + m16)*40 + q*8]);
    }
    #pragma unroll
    for (int rt = 0; rt < 4; rt++)
      #pragma unroll
      for (int ct = 0; ct < 4; ct++)
        acc[rt][ct] = __builtin_amdgcn_mfma_f32_16x16x32_bf16(af[rt], bfv[ct], acc[rt][ct], 0, 0, 0);
    __syncthreads();
  }

  #pragma unroll
  for (int rt = 0; rt < 4; rt++){
    #pragma unroll
    for (int rr = 0; rr < 4; rr++){
      int row = row0 + wr + rt*16 + q*4 + rr;
      if (row >= M) continue;
      #pragma unroll
      for (int ct = 0; ct < 4; ct++){
        int col = col0 + wc + ct*16 + m16;
        if (col >= Ncols) continue;
        float v = acc[rt][ct][rr] + (bias ? bias[col] : 0.f);
        if (OUTMODE == 1)      ((float*)Cp)[row*Cstride + col] = v;
        else if (OUTMODE == 0) ((bf16*)Cp)[row*Cstride + col] = f2b(v);
        else {
          if (col < 80) ((bf16*)Cp )[row*80 + col]      = f2b(v);
          else          ((bf16*)Cp2)[row*80 + col - 80] = f2b(v);
        }
      }
    }
  }
}

// ------------------------------------------------------------------ aggregation
// one wave per node; lane<40 handles feature pair (2*lane, 2*lane+1); edge loop unrolled x8
__global__ __launch_bounds__(256) void k_agg(const bf16* __restrict__ Ua,
                      const bf16* __restrict__ Ub,
                      const int* __restrict__ rowptr,
                      const int* __restrict__ colidx, bf16* __restrict__ agg)
{
  int n = blockIdx.x*4 + (threadIdx.x >> 6);
  int lane = threadIdx.x & 63;
  if (n >= NN) return;
  int rs = rowptr[n], re = rowptr[n+1];
  int deg = re - rs;
  bool act = lane < 40;
  int fo = lane*2;
  float a0 = 0.f, a1 = 0.f;
  if (act){
    unsigned ua = *(const unsigned*)(Ua + n*80 + fo);
    a0 = __uint_as_float(ua << 16);
    a1 = __uint_as_float(ua & 0xffff0000u);
  }
  float sb0=0.f, sb1=0.f, sq0=0.f, sq1=0.f;
  float mn0=1e30f, mn1=1e30f, mx0=-1e30f, mx1=-1e30f;

#define ACC(u) { \
    float b0 = __uint_as_float((u) << 16); \
    float b1 = __uint_as_float((u) & 0xffff0000u); \
    sb0 += b0; sq0 += b0*b0; mn0 = fminf(mn0,b0); mx0 = fmaxf(mx0,b0); \
    sb1 += b1; sq1 += b1*b1; mn1 = fminf(mn1,b1); mx1 = fmaxf(mx1,b1); }

  int e = rs;
  for (; e + 8 <= re; e += 8){
    int s[8];
    #pragma unroll
    for (int j = 0; j < 8; j++) s[j] = colidx[e + j];
    unsigned u[8] = {};
    if (act){
      #pragma unroll
      for (int j = 0; j < 8; j++) u[j] = *(const unsigned*)(Ub + s[j]*80 + fo);
    }
    #pragma unroll
    for (int j = 0; j < 8; j++) ACC(u[j]);
  }
  for (; e + 4 <= re; e += 4){
    int s[4];
    #pragma unroll
    for (int j = 0; j < 4; j++) s[j] = colidx[e + j];
    unsigned u[4] = {};
    if (act){
      #pragma unroll
      for (int j = 0; j < 4; j++) u[j] = *(const unsigned*)(Ub + s[j]*80 + fo);
    }
    #pragma unroll
    for (int j = 0; j < 4; j++) ACC(u[j]);
  }
  for (; e < re; e++){
    int s = colidx[e];
    unsigned u = 0u;
    if (act) u = *(const unsigned*)(Ub + s*80 + fo);
    ACC(u);
  }
#undef ACC

  if (!act) return;
  float degc = (float)(deg > 0 ? deg : 1);
  float inv = 1.f/degc;
  float dm = (float)deg;
  float mean0 = (dm*a0 + sb0)*inv;
  float mean1 = (dm*a1 + sb1)*inv;
  float v0 = (dm*a0*a0 + 2.f*a0*sb0 + sq0)*inv - mean0*mean0;
  float v1 = (dm*a1*a1 + 2.f*a1*sb1 + sq1)*inv - mean1*mean1;
  float sd0 = sqrtf(fmaxf(v0,0.f)+1e-5f);
  float sd1 = sqrtf(fmaxf(v1,0.f)+1e-5f);
  float lo0 = deg>0 ? a0+mn0 : 0.f;
  float lo1 = deg>0 ? a1+mn1 : 0.f;
  float hi0 = deg>0 ? a0+mx0 : 0.f;
  float hi1 = deg>0 ? a1+mx1 : 0.f;
  unsigned* ag = (unsigned*)(agg + n*320 + fo);
  ag[0]   = pk(mean0, mean1);
  ag[40]  = pk(lo0, lo1);
  ag[80]  = pk(hi0, hi1);
  ag[120] = pk(sd0, sd1);
}

// h += relu(P + sc*Q + inv*R + bias2)   (U stride 240: P|Q|R)
__global__ void k_combine(const bf16* __restrict__ U, const float* __restrict__ b2v,
                          const float* __restrict__ scf, const float* __restrict__ invf,
                          float* __restrict__ h){
  int gid = blockIdx.x*256 + threadIdx.x;
  if (gid >= NN*FD) return;
  int n = gid / FD, f = gid - n*FD;
  const bf16* xr = U + n*240;
  float o = b2f(xr[f]) + scf[n]*b2f(xr[80 + f]) + invf[n]*b2f(xr[160 + f]) + b2v[f];
  h[gid] += fmaxf(o, 0.f);
}

// ------------------------------------------------------------------ fused mean-pool + head
__global__ __launch_bounds__(128) void k_poolmlp(const float* __restrict__ h,
                        const int* __restrict__ batch,
                        const void* __restrict__ mlpW, const void* __restrict__ mlpb,
                        const int* __restrict__ flag, void* __restrict__ outp){
  __shared__ float sred[128];
  __shared__ int sb[2];
  int g = blockIdx.x;
  int t = threadIdx.x;
  if (t < 2){
    int target = g + t;
    int lo = 0, hi = NN;
    while (lo < hi){ int mid = (lo + hi) >> 1; if (batch[mid] < target) lo = mid + 1; else hi = mid; }
    sb[t] = lo;
  }
  __syncthreads();
  int lo = sb[0], hi = sb[1];
  float s = 0.f;
  if (t < 80)
    for (int n = lo; n < hi; n++) s += h[n*80 + t];
  int fl = flag[0];
  float wv = (t < 80) ? rdw(mlpW, t, fl) : 0.f;
  sred[t] = s * wv;
  __syncthreads();
  for (int off = 64; off > 0; off >>= 1){
    if (t < off) sred[t] += sred[t + off];
    __syncthreads();
  }
  if (t == 0){
    float cnt = (float)(hi - lo); if (cnt < 1.f) cnt = 1.f;
    float r = sred[0]/cnt + rdw(mlpb, 0, fl);
    if (fl) ((float*)outp)[g] = r;
    else    ((bf16*)outp)[g] = f2b(r);
  }
}

// ------------------------------------------------------------------ launch
extern "C" void kernel_launch(void* const* d_in, const int* in_sizes, int n_in,
                              void* d_out, int out_size, void* d_ws, size_t ws_size,
                              hipStream_t stream)
{
  const int*  x     = (const int*) d_in[0];
  const int*  ei    = (const int*) d_in[1];
  const int*  batch = (const int*) d_in[2];
  const void* avgp  = d_in[3];
  const void* aemb  = d_in[4];
  const void* preW  = d_in[5];
  const void* preb  = d_in[6];
  const void* postW = d_in[7];
  const void* postb = d_in[8];
  const void* linW  = d_in[9];
  const void* linb  = d_in[10];
  const void* bng   = d_in[11];
  const void* bnb   = d_in[12];
  const void* bnm   = d_in[13];
  const void* bnv   = d_in[14];
  const void* mlpW  = d_in[15];
  const void* mlpb  = d_in[16];

  char* w = (char*)d_ws;
  int*   deg    = (int*)  (w + 0);            //   200,000  (zeroed)
  int*   cursor = (int*)  (w + 200000);       //   200,000  (zeroed)
  int*   flag   = (int*)  (w + 400000);       //       256  (zeroed; zero region = 400,256 B)
  int*   bsum   = (int*)  (w + 400256);       //     1,024
  int*   rowptr = (int*)  (w + 401280);       //   200,064
  int*   colidx = (int*)  (w + 601344);       // 3,200,000
  float* scf    = (float*)(w + 3801344);      //   200,000
  float* invf   = (float*)(w + 4001344);      //   200,000
  float* bias1  = (float*)(w + 4201344);      //     2,560
  float* bias2  = (float*)(w + 4203904);      //     1,280
  bf16*  Btl    = (bf16*) (w + 4205184);      //    61,440
  bf16*  Bt1    = (bf16*) (w + 4266624);      //   122,880
  bf16*  Bt2    = (bf16*) (w + 4389504);      //   798,720
  float* h      = (float*)(w + 5188224);      // 16,000,000  f32 [N,80]
  bf16*  Ua     = (bf16*) (w + 21188224);     //  8,000,000  bf16 [N,80] (a)
  bf16*  Ub     = (bf16*) (w + 29188224);     //  8,000,000  bf16 [N,80] (b)
  bf16*  U240   = (bf16*) (w + 21188224);     // 24,000,000  bf16 [N,240] PQR (overlays Ua/Ub)
  bf16*  agg    = (bf16*) (w + 45188224);     // 32,000,000  bf16 [N,320]
  bf16*  pwb    = (bf16*) (w + 45188224);     //   665,600   (overlay in agg, used pre-loop)
  float* Wf     = (float*)(w + 45853824);     // 1,331,200   (overlay in agg)
  // total 77,188,224 B

  k_zero <<<(100064 + 255)/256, 256, 0, stream>>>((int*)w, 100064);
  k_probe<<<16, 256, 0, stream>>>(aemb, flag);

  k_prep_all<<<1662, 256, 0, stream>>>(preW, preb, postW, postb, linW, linb,
                                       bng, bnb, bnm, bnv, flag,
                                       pwb, Btl, Bt1, bias1, bias2);

  // batched prep GEMM over 4 layers: Wf[i] = postW[i](bf16) @ Btl[i]^T
  k_mgemm<0,1><<<dim3(9,1,4), 256, 0, stream>>>(
      pwb, 80, 80, nullptr, 0, 0,
      Btl, 96, 80, nullptr, Wf, nullptr, 80, 1040, 96,
      166400, 15360, 332800);
  k_prep_Bt2<<<(4*240*416 + 255)/256, 256, 0, stream>>>(Wf, Bt2);

  k_atom <<<(NN*FD + 255)/256, 256, 0, stream>>>(x, aemb, flag, h);
  k_deg  <<<(NE + 255)/256, 256, 0, stream>>>(ei, deg);
  k_scan1<<<196, 256, 0, stream>>>(deg, bsum);
  k_scan2<<<1, 256, 0, stream>>>(bsum, rowptr);
  k_scan3<<<196, 256, 0, stream>>>(deg, bsum, avgp, flag, rowptr, scf, invf);
  k_scatter<<<(NE + 255)/256, 256, 0, stream>>>(ei, rowptr, cursor, colidx);

  for (int i = 0; i < 4; i++){
    k_mgemm<1,2><<<dim3(391,2,1), 256, 0, stream>>>(
        h, 80, 80, nullptr, 0, 0,
        Bt1 + i*15360, 96, 160, bias1 + i*160, Ua, Ub, 0, NN, 96,
        0, 0, 0);
    k_agg<<<12500, 256, 0, stream>>>(Ua, Ub, rowptr, colidx, agg);
    k_mgemm<1,0><<<dim3(391,2,1), 256, 0, stream>>>(
        h, 80, 80, agg, 320, 320,
        Bt2 + i*99840, 416, 240, nullptr, U240, nullptr, 240, NN, 416,
        0, 0, 0);
    k_combine<<<(NN*FD + 255)/256, 256, 0, stream>>>(U240, bias2 + i*80, scf, invf, h);
  }

  k_poolmlp<<<NGR, 128, 0, stream>>>(h, batch, mlpW, mlpb, flag, d_out);
}

// Round 7
// 617.077 us; speedup vs baseline: 2.4962x; 1.2519x over previous
//
#include <hip/hip_runtime.h>
#include <hip/hip_bf16.h>

#define NN 50000
#define NE 800000
#define FD 80
#define NGR 1024
#define NF 9

using bf16 = __hip_bfloat16;
typedef __attribute__((ext_vector_type(8))) short bf16x8;
typedef __attribute__((ext_vector_type(4))) float f32x4;

static __device__ __forceinline__ float b2f(bf16 v){ return __bfloat162float(v); }
static __device__ __forceinline__ bf16 f2b(float v){ return __float2bfloat16(v); }
static __device__ __forceinline__ float rdw(const void* p, int i, int fl){
  return fl ? ((const float*)p)[i] : b2f(((const bf16*)p)[i]);
}
static __device__ __forceinline__ unsigned pk(float a, float b){
  bf16 x = f2b(a), y = f2b(b);
  return (unsigned)*(unsigned short*)&x | ((unsigned)*(unsigned short*)&y << 16);
}

// ------------------------------------------------------------------ utility
__global__ void k_zero(int* __restrict__ p, int n){
  int t = blockIdx.x*256 + threadIdx.x;
  if (t < n) p[t] = 0;
}

__global__ void k_probe(const void* __restrict__ emb, int* __restrict__ flag){
  int t = blockIdx.x*256 + threadIdx.x;
  float v = b2f(((const bf16*)emb)[t]);
  if (!(fabsf(v) < 1e4f)) atomicOr(flag, 1);
}

// ------------------------------------------------------------------ fused weight prep
// blocks [0,1300): cvt_pw; [1300,1420): prep_lin; [1420,1660): prep_Bt1; [1660,1662): prep_bias2
__global__ __launch_bounds__(256) void k_prep_all(
    const void* __restrict__ preW, const void* __restrict__ preb,
    const void* __restrict__ postW, const void* __restrict__ postb,
    const void* __restrict__ linW, const void* __restrict__ linb,
    const void* __restrict__ bng, const void* __restrict__ bnb,
    const void* __restrict__ bnm, const void* __restrict__ bnv,
    const int* __restrict__ flag,
    bf16* __restrict__ pwb, bf16* __restrict__ Btl, bf16* __restrict__ Bt1,
    float* __restrict__ bias1, float* __restrict__ bias2)
{
  int fl = flag[0];
  int b = blockIdx.x;
  if (b < 1300){
    int t = b*256 + threadIdx.x;
    pwb[t] = f2b(rdw(postW, t, fl));
  } else if (b < 1420){
    int t = (b - 1300)*256 + threadIdx.x;
    int j = t % 96, c = (t/96) % 80, i = t/(96*80);
    float v = 0.f;
    if (j < 80){
      float gs = rdw(bng, i*80 + c, fl) * rsqrtf(rdw(bnv, i*80 + c, fl) + 1e-5f);
      v = rdw(linW, i*6400 + j*80 + c, fl) * gs;
    }
    Btl[t] = f2b(v);
  } else if (b < 1660){
    int t = (b - 1420)*256 + threadIdx.x;
    int k = t % 96, c = (t/96) % 160, i = t/(96*160);
    float v = 0.f;
    if (k < 80)
      v = (c < 80) ? rdw(preW, (i*160 + k)*80 + c, fl)
                   : rdw(preW, (i*160 + 80 + k)*80 + (c - 80), fl);
    Bt1[t] = f2b(v);
    if (k == 0) bias1[i*160 + c] = (c < 80) ? rdw(preb, i*80 + c, fl) : 0.f;
  } else {
    int t = (b - 1660)*256 + threadIdx.x;
    if (t >= 4*80) return;
    int i = t / 80, f = t - i*80;
    float s = 0.f;
    for (int j = 0; j < 80; j++)
      s += rdw(postb, i*80 + j, fl) * rdw(linW, (i*80 + j)*80 + f, fl);
    s += rdw(linb, t, fl);
    float gs = rdw(bng, t, fl) * rsqrtf(rdw(bnv, t, fl) + 1e-5f);
    bias2[t] = (s - rdw(bnm, t, fl)) * gs + rdw(bnb, t, fl);
  }
}

// Bt2[i][c][k] (c<240 cols, 416-k) from Wf (f32 [i][1040][80]).
__global__ void k_prep_Bt2(const float* __restrict__ Wf, bf16* __restrict__ Bt2){
  int t = blockIdx.x*256 + threadIdx.x;
  if (t >= 4*240*416) return;
  int k = t % 416;
  int c = (t/416) % 240;
  int i = t/(416*240);
  float v = 0.f;
  if (k < 400){
    int blk = c/80, f = c - blk*80;
    if (blk == 0) v = Wf[(i*1040 + k)*80 + f];
    else if (k >= 80){
      int row = (blk == 1 ? 400 : 720) + (k - 80);
      v = Wf[(i*1040 + row)*80 + f];
    }
  }
  Bt2[t] = f2b(v);
}

// ------------------------------------------------------------------ graph prep
__global__ void k_atom(const int* __restrict__ x, const void* __restrict__ emb,
                       const int* __restrict__ flag, float* __restrict__ h){
  int fl = flag[0];
  int gid = blockIdx.x*256 + threadIdx.x;
  if (gid >= NN*FD) return;
  int n = gid / FD, f = gid - n*FD;
  float s = 0.f;
  #pragma unroll
  for (int c = 0; c < NF; c++){
    int row = x[n*NF + c];
    s += rdw(emb, (c*119 + row)*FD + f, fl);
  }
  h[gid] = s;
}

__global__ void k_deg(const int* __restrict__ ei, int* __restrict__ deg){
  int e = blockIdx.x*256 + threadIdx.x;
  if (e < NE) atomicAdd(&deg[ei[NE + e]], 1);
}

__global__ __launch_bounds__(256) void k_scan1(const int* __restrict__ deg, int* __restrict__ bsum){
  __shared__ int buf[256];
  int idx = blockIdx.x*256 + threadIdx.x;
  buf[threadIdx.x] = (idx < NN) ? deg[idx] : 0;
  __syncthreads();
  for (int off = 128; off > 0; off >>= 1){
    if (threadIdx.x < off) buf[threadIdx.x] += buf[threadIdx.x + off];
    __syncthreads();
  }
  if (threadIdx.x == 0) bsum[blockIdx.x] = buf[0];
}

__global__ __launch_bounds__(256) void k_scan2(int* __restrict__ bsum, int* __restrict__ rowptr){
  __shared__ int buf[256];
  int t = threadIdx.x;
  int v = (t < 196) ? bsum[t] : 0;
  buf[t] = v;
  __syncthreads();
  for (int off = 1; off < 256; off <<= 1){
    int xv = (t >= off) ? buf[t - off] : 0;
    __syncthreads();
    buf[t] += xv;
    __syncthreads();
  }
  if (t < 196) bsum[t] = buf[t] - v;
  if (t == 255) rowptr[NN] = buf[255];
}

__global__ __launch_bounds__(256) void k_scan3(const int* __restrict__ deg,
                        const int* __restrict__ bsum, const void* __restrict__ avgp,
                        const int* __restrict__ flag, int* __restrict__ rowptr,
                        float* __restrict__ scf, float* __restrict__ invf){
  __shared__ int buf[256];
  int t = threadIdx.x;
  int idx = blockIdx.x*256 + t;
  int v = (idx < NN) ? deg[idx] : 0;
  buf[t] = v;
  __syncthreads();
  for (int off = 1; off < 256; off <<= 1){
    int xv = (t >= off) ? buf[t - off] : 0;
    __syncthreads();
    buf[t] += xv;
    __syncthreads();
  }
  if (idx < NN){
    rowptr[idx] = bsum[blockIdx.x] + buf[t] - v;
    float degc = (float)(v > 0 ? v : 1);
    float logd = logf(degc + 1.f);
    float avg = rdw(avgp, 0, flag[0]);
    scf[idx] = logd / avg;
    invf[idx] = avg / logd;
  }
}

__global__ void k_scatter(const int* __restrict__ ei, const int* __restrict__ rowptr,
                          int* __restrict__ cursor, int* __restrict__ colidx){
  int e = blockIdx.x*256 + threadIdx.x;
  if (e >= NE) return;
  int d = ei[NE + e];
  int pos = rowptr[d] + atomicAdd(&cursor[d], 1);
  colidx[pos] = ei[e];
}

// ------------------------------------------------------------------ MFMA GEMM
// 32-row x 256-col block tile, 4 waves (wave w = cols w*64..w*64+63), K-loop with
// register prefetch. OUTMODE: 1 = f32 out (stride Cstride); 2 = split bf16 (Ua/Ub);
// 3 = fused PNA epilogue: h += relu(P + sc*Q + inv*R + bias) via LDS staging.
// A rows: k<KA from A1 (f32 if AF32, stride s1); KA<=k<KA+KB from A2 (bf16, s2); else 0.
template<int AF32, int OUTMODE>
__global__ __launch_bounds__(256) void k_mgemm(
    const void* __restrict__ A1p, int s1, int KA,
    const bf16* __restrict__ A2, int s2, int KB,
    const bf16* __restrict__ Btp, int Bts, int Ncols,
    const float* __restrict__ bias,
    void* __restrict__ Cbase, void* __restrict__ Cp2, int Cstride, int M, int K,
    const float* __restrict__ scf, const float* __restrict__ invf,
    int lA1b, int lBtb, int lCb)
{
  const void* A1 = (const char*)A1p + (size_t)blockIdx.z*lA1b;
  const bf16* Bt = (const bf16*)((const char*)Btp + (size_t)blockIdx.z*lBtb);
  void* Cp = (char*)Cbase + (size_t)blockIdx.z*lCb;

  __shared__ char smem[23040];
  short* As = (short*)smem;            // 32 x 40 shorts = 2560 B
  short* Bs = (short*)(smem + 2560);   // 256 x 40 shorts = 20480 B
  bf16*  eL = (bf16*)smem;             // epilogue staging 32 x 248 bf16 (reuse)

  const int tid = threadIdx.x;
  const int row0 = blockIdx.x * 32;
  const int wave = tid >> 6, lane = tid & 63;
  const int wc = wave * 64;
  const int m16 = lane & 15, q = lane >> 4;

  // A loader (threads 0..127): row ra, chunk ka*8; B loader (all): 4 chunks
  const int ra = tid >> 2, ka = (tid & 3) * 8;
  const int cb = tid >> 2, kb = (tid & 3) * 8;

  f32x4 acc[2][4] = {};
  uint4 pa; pa.x = pa.y = pa.z = pa.w = 0u;
  uint4 pb[4];

  const int nk = (K + 31) >> 5;

  // ---- load k-tile 0 into regs
  {
    int kg = ka;
    pa.x = pa.y = pa.z = pa.w = 0u;
    if (tid < 128){
      int grow = row0 + ra;
      if (grow < M){
        if (kg < KA){
          if (AF32){
            const float* ap = (const float*)A1 + grow*s1 + kg;
            float4 f0 = *(const float4*)ap;
            float4 f1 = *(const float4*)(ap + 4);
            pa.x = pk(f0.x, f0.y); pa.y = pk(f0.z, f0.w);
            pa.z = pk(f1.x, f1.y); pa.w = pk(f1.z, f1.w);
          } else {
            pa = *(const uint4*)((const bf16*)A1 + grow*s1 + kg);
          }
        } else if (kg - KA < KB){
          pa = *(const uint4*)(A2 + grow*s2 + (kg - KA));
        }
      }
    }
    #pragma unroll
    for (int j = 0; j < 4; j++){
      int col = cb + j*64;
      pb[j].x = pb[j].y = pb[j].z = pb[j].w = 0u;
      if (col < Ncols) pb[j] = *(const uint4*)(Bt + col*Bts + kb);
    }
  }

  for (int ks = 0; ks < nk; ks++){
    // ---- regs -> LDS
    if (tid < 128) *(uint4*)(&As[ra*40 + ka]) = pa;
    #pragma unroll
    for (int j = 0; j < 4; j++)
      *(uint4*)(&Bs[(cb + j*64)*40 + kb]) = pb[j];
    __syncthreads();

    // ---- prefetch next k-tile (overlaps ds_read + MFMA below)
    if (ks + 1 < nk){
      int k0 = (ks + 1) << 5;
      int kg = k0 + ka;
      pa.x = pa.y = pa.z = pa.w = 0u;
      if (tid < 128){
        int grow = row0 + ra;
        if (grow < M){
          if (kg < KA){
            if (AF32){
              const float* ap = (const float*)A1 + grow*s1 + kg;
              float4 f0 = *(const float4*)ap;
              float4 f1 = *(const float4*)(ap + 4);
              pa.x = pk(f0.x, f0.y); pa.y = pk(f0.z, f0.w);
              pa.z = pk(f1.x, f1.y); pa.w = pk(f1.z, f1.w);
            } else {
              pa = *(const uint4*)((const bf16*)A1 + grow*s1 + kg);
            }
          } else if (kg - KA < KB){
            pa = *(const uint4*)(A2 + grow*s2 + (kg - KA));
          }
        }
      }
      int kgb = k0 + kb;
      #pragma unroll
      for (int j = 0; j < 4; j++){
        int col = cb + j*64;
        pb[j].x = pb[j].y = pb[j].z = pb[j].w = 0u;
        if (col < Ncols) pb[j] = *(const uint4*)(Bt + col*Bts + kgb);
      }
    }

    // ---- fragments + MFMA
    bf16x8 af[2], bfv[4];
    #pragma unroll
    for (int rt = 0; rt < 2; rt++)
      af[rt] = *(const bf16x8*)(&As[(rt*16 + m16)*40 + q*8]);
    #pragma unroll
    for (int ct = 0; ct < 4; ct++)
      bfv[ct] = *(const bf16x8*)(&Bs[(wc + ct*16 + m16)*40 + q*8]);
    #pragma unroll
    for (int rt = 0; rt < 2; rt++)
      #pragma unroll
      for (int ct = 0; ct < 4; ct++)
        acc[rt][ct] = __builtin_amdgcn_mfma_f32_16x16x32_bf16(af[rt], bfv[ct], acc[rt][ct], 0, 0, 0);
    __syncthreads();
  }

  // ---- epilogue
  if (OUTMODE == 3){
    // stage P|Q|R (bf16) in LDS, then combine into h
    #pragma unroll
    for (int rt = 0; rt < 2; rt++){
      #pragma unroll
      for (int ct = 0; ct < 4; ct++){
        int col = wc + ct*16 + m16;
        if (col >= 240) continue;
        #pragma unroll
        for (int rr = 0; rr < 4; rr++){
          int r = rt*16 + q*4 + rr;
          eL[r*248 + col] = f2b(acc[rt][ct][rr]);   // bf16* store (bit-store, not int-trunc)
        }
      }
    }
    __syncthreads();
    float* hp = (float*)Cp;
    #pragma unroll
    for (int i = 0; i < 10; i++){
      int idx = tid + i*256;
      int r = idx / 80, c = idx - r*80;
      int row = row0 + r;
      if (row < M){
        float P = b2f(eL[r*248 + c]);
        float Q = b2f(eL[r*248 + 80 + c]);
        float R = b2f(eL[r*248 + 160 + c]);
        float o = P + scf[row]*Q + invf[row]*R + bias[c];
        hp[row*80 + c] += fmaxf(o, 0.f);
      }
    }
  } else {
    #pragma unroll
    for (int rt = 0; rt < 2; rt++){
      #pragma unroll
      for (int rr = 0; rr < 4; rr++){
        int row = row0 + rt*16 + q*4 + rr;
        if (row >= M) continue;
        #pragma unroll
        for (int ct = 0; ct < 4; ct++){
          int col = wc + ct*16 + m16;
          if (col >= Ncols) continue;
          float v = acc[rt][ct][rr] + (bias ? bias[col] : 0.f);
          if (OUTMODE == 1) ((float*)Cp)[row*Cstride + col] = v;
          else {
            if (col < 80) ((bf16*)Cp )[row*80 + col]      = f2b(v);
            else          ((bf16*)Cp2)[row*80 + col - 80] = f2b(v);
          }
        }
      }
    }
  }
}

// ------------------------------------------------------------------ aggregation
// 3 nodes/wave: lane/20 = node slot, (lane%20)*4 = feature offset (uint2 = 4 bf16)
__global__ __launch_bounds__(256) void k_agg(const bf16* __restrict__ Ua,
                      const bf16* __restrict__ Ub,
                      const int* __restrict__ rowptr,
                      const int* __restrict__ colidx, bf16* __restrict__ agg)
{
  int lane = threadIdx.x & 63;
  int slot = lane / 20;
  int n = blockIdx.x*12 + (threadIdx.x >> 6)*3 + slot;
  if (slot >= 3 || n >= NN) return;
  int fo = (lane - slot*20) * 4;
  int rs = rowptr[n], re = rowptr[n+1];
  int deg = re - rs;

  float a[4];
  {
    uint2 ua = *(const uint2*)(Ua + n*80 + fo);
    a[0] = __uint_as_float(ua.x << 16);
    a[1] = __uint_as_float(ua.x & 0xffff0000u);
    a[2] = __uint_as_float(ua.y << 16);
    a[3] = __uint_as_float(ua.y & 0xffff0000u);
  }
  float sb[4] = {0.f,0.f,0.f,0.f}, sq[4] = {0.f,0.f,0.f,0.f};
  float mn[4] = {1e30f,1e30f,1e30f,1e30f}, mx[4] = {-1e30f,-1e30f,-1e30f,-1e30f};

#define ACC2(w, o) { \
    float b0 = __uint_as_float((w) << 16); \
    float b1 = __uint_as_float((w) & 0xffff0000u); \
    sb[o] += b0; sq[o] += b0*b0; mn[o] = fminf(mn[o],b0); mx[o] = fmaxf(mx[o],b0); \
    sb[o+1] += b1; sq[o+1] += b1*b1; mn[o+1] = fminf(mn[o+1],b1); mx[o+1] = fmaxf(mx[o+1],b1); }

  for (int e = rs; e < re; e += 8){
    int cnt = re - e; if (cnt > 8) cnt = 8;
    int s[8];
    #pragma unroll
    for (int j = 0; j < 8; j++) s[j] = (j < cnt) ? colidx[e + j] : s[0];
    uint2 u[8];
    #pragma unroll
    for (int j = 0; j < 8; j++) u[j] = *(const uint2*)(Ub + s[j]*80 + fo);
    #pragma unroll
    for (int j = 0; j < 8; j++){
      if (j < cnt){ ACC2(u[j].x, 0); ACC2(u[j].y, 2); }
    }
  }
#undef ACC2

  float degc = (float)(deg > 0 ? deg : 1);
  float inv = 1.f/degc;
  float dm = (float)deg;
  float mean0, mean1, v0, v1, sd0, sd1, lo0, lo1, hi0, hi1;

  mean0 = (dm*a[0] + sb[0])*inv; mean1 = (dm*a[1] + sb[1])*inv;
  v0 = (dm*a[0]*a[0] + 2.f*a[0]*sb[0] + sq[0])*inv - mean0*mean0;
  v1 = (dm*a[1]*a[1] + 2.f*a[1]*sb[1] + sq[1])*inv - mean1*mean1;
  sd0 = sqrtf(fmaxf(v0,0.f)+1e-5f); sd1 = sqrtf(fmaxf(v1,0.f)+1e-5f);
  lo0 = deg>0 ? a[0]+mn[0] : 0.f; lo1 = deg>0 ? a[1]+mn[1] : 0.f;
  hi0 = deg>0 ? a[0]+mx[0] : 0.f; hi1 = deg>0 ? a[1]+mx[1] : 0.f;
  unsigned o0 = pk(mean0, mean1);
  unsigned l0 = pk(lo0, lo1), h0 = pk(hi0, hi1), t0 = pk(sd0, sd1);

  mean0 = (dm*a[2] + sb[2])*inv; mean1 = (dm*a[3] + sb[3])*inv;
  v0 = (dm*a[2]*a[2] + 2.f*a[2]*sb[2] + sq[2])*inv - mean0*mean0;
  v1 = (dm*a[3]*a[3] + 2.f*a[3]*sb[3] + sq[3])*inv - mean1*mean1;
  sd0 = sqrtf(fmaxf(v0,0.f)+1e-5f); sd1 = sqrtf(fmaxf(v1,0.f)+1e-5f);
  lo0 = deg>0 ? a[2]+mn[2] : 0.f; lo1 = deg>0 ? a[3]+mn[3] : 0.f;
  hi0 = deg>0 ? a[2]+mx[2] : 0.f; hi1 = deg>0 ? a[3]+mx[3] : 0.f;
  unsigned o1 = pk(mean0, mean1);
  unsigned l1 = pk(lo0, lo1), h1 = pk(hi0, hi1), t1 = pk(sd0, sd1);

  bf16* ag = agg + n*320 + fo;
  *(uint2*)(ag)       = make_uint2(o0, o1);
  *(uint2*)(ag + 80)  = make_uint2(l0, l1);
  *(uint2*)(ag + 160) = make_uint2(h0, h1);
  *(uint2*)(ag + 240) = make_uint2(t0, t1);
}

// ------------------------------------------------------------------ fused mean-pool + head
__global__ __launch_bounds__(128) void k_poolmlp(const float* __restrict__ h,
                        const int* __restrict__ batch,
                        const void* __restrict__ mlpW, const void* __restrict__ mlpb,
                        const int* __restrict__ flag, void* __restrict__ outp){
  __shared__ float sred[128];
  __shared__ int sb[2];
  int g = blockIdx.x;
  int t = threadIdx.x;
  if (t < 2){
    int target = g + t;
    int lo = 0, hi = NN;
    while (lo < hi){ int mid = (lo + hi) >> 1; if (batch[mid] < target) lo = mid + 1; else hi = mid; }
    sb[t] = lo;
  }
  __syncthreads();
  int lo = sb[0], hi = sb[1];
  float s = 0.f;
  if (t < 80)
    for (int n = lo; n < hi; n++) s += h[n*80 + t];
  int fl = flag[0];
  float wv = (t < 80) ? rdw(mlpW, t, fl) : 0.f;
  sred[t] = s * wv;
  __syncthreads();
  for (int off = 64; off > 0; off >>= 1){
    if (t < off) sred[t] += sred[t + off];
    __syncthreads();
  }
  if (t == 0){
    float cnt = (float)(hi - lo); if (cnt < 1.f) cnt = 1.f;
    float r = sred[0]/cnt + rdw(mlpb, 0, fl);
    if (fl) ((float*)outp)[g] = r;
    else    ((bf16*)outp)[g] = f2b(r);
  }
}

// ------------------------------------------------------------------ launch
extern "C" void kernel_launch(void* const* d_in, const int* in_sizes, int n_in,
                              void* d_out, int out_size, void* d_ws, size_t ws_size,
                              hipStream_t stream)
{
  const int*  x     = (const int*) d_in[0];
  const int*  ei    = (const int*) d_in[1];
  const int*  batch = (const int*) d_in[2];
  const void* avgp  = d_in[3];
  const void* aemb  = d_in[4];
  const void* preW  = d_in[5];
  const void* preb  = d_in[6];
  const void* postW = d_in[7];
  const void* postb = d_in[8];
  const void* linW  = d_in[9];
  const void* linb  = d_in[10];
  const void* bng   = d_in[11];
  const void* bnb   = d_in[12];
  const void* bnm   = d_in[13];
  const void* bnv   = d_in[14];
  const void* mlpW  = d_in[15];
  const void* mlpb  = d_in[16];

  char* w = (char*)d_ws;
  int*   deg    = (int*)  (w + 0);            //   200,000  (zeroed)
  int*   cursor = (int*)  (w + 200000);       //   200,000  (zeroed)
  int*   flag   = (int*)  (w + 400000);       //       256  (zero region = 400,256 B)
  int*   bsum   = (int*)  (w + 400256);       //     1,024
  int*   rowptr = (int*)  (w + 401280);       //   200,064
  int*   colidx = (int*)  (w + 601344);       // 3,200,000
  float* scf    = (float*)(w + 3801344);      //   200,000
  float* invf   = (float*)(w + 4001344);      //   200,000
  float* bias1  = (float*)(w + 4201344);      //     2,560
  float* bias2  = (float*)(w + 4203904);      //     1,280
  bf16*  Btl    = (bf16*) (w + 4205184);      //    61,440
  bf16*  Bt1    = (bf16*) (w + 4266624);      //   122,880
  bf16*  Bt2    = (bf16*) (w + 4389504);      //   798,720
  float* h      = (float*)(w + 5188224);      // 16,000,000  f32 [N,80]
  bf16*  Ua     = (bf16*) (w + 21188224);     //  8,000,000  bf16 [N,80]
  bf16*  Ub     = (bf16*) (w + 29188224);     //  8,000,000  bf16 [N,80]
  bf16*  agg    = (bf16*) (w + 45188224);     // 32,000,000  bf16 [N,320]
  bf16*  pwb    = (bf16*) (w + 45188224);     //   665,600   (overlay in agg, pre-loop use)
  float* Wf     = (float*)(w + 45853824);     // 1,331,200   (overlay in agg)
  // total 77,188,224 B

  k_zero <<<(100064 + 255)/256, 256, 0, stream>>>((int*)w, 100064);
  k_probe<<<16, 256, 0, stream>>>(aemb, flag);

  k_prep_all<<<1662, 256, 0, stream>>>(preW, preb, postW, postb, linW, linb,
                                       bng, bnb, bnm, bnv, flag,
                                       pwb, Btl, Bt1, bias1, bias2);

  // Wf[i] = postW[i](bf16) @ Btl[i]^T   (f32 out)
  k_mgemm<0,1><<<dim3(33,1,4), 256, 0, stream>>>(
      pwb, 80, 80, nullptr, 0, 0,
      Btl, 96, 80, nullptr, Wf, nullptr, 80, 1040, 96,
      nullptr, nullptr, 166400, 15360, 332800);
  k_prep_Bt2<<<(4*240*416 + 255)/256, 256, 0, stream>>>(Wf, Bt2);

  k_atom <<<(NN*FD + 255)/256, 256, 0, stream>>>(x, aemb, flag, h);
  k_deg  <<<(NE + 255)/256, 256, 0, stream>>>(ei, deg);
  k_scan1<<<196, 256, 0, stream>>>(deg, bsum);
  k_scan2<<<1, 256, 0, stream>>>(bsum, rowptr);
  k_scan3<<<196, 256, 0, stream>>>(deg, bsum, avgp, flag, rowptr, scf, invf);
  k_scatter<<<(NE + 255)/256, 256, 0, stream>>>(ei, rowptr, cursor, colidx);

  const int gx = (NN + 31)/32;   // 1563
  for (int i = 0; i < 4; i++){
    // GEMM1: [h] @ Bt1 -> Ua|Ub  (K=96, Ncols=160)
    k_mgemm<1,2><<<dim3(gx,1,1), 256, 0, stream>>>(
        h, 80, 80, nullptr, 0, 0,
        Bt1 + i*15360, 96, 160, bias1 + i*160, Ua, Ub, 0, NN, 96,
        nullptr, nullptr, 0, 0, 0);
    k_agg<<<(NN + 11)/12, 256, 0, stream>>>(Ua, Ub, rowptr, colidx, agg);
    // GEMM2 fused: h += relu(P + sc*Q + inv*R + bias2)  (K=416, Ncols=240)
    k_mgemm<1,3><<<dim3(gx,1,1), 256, 0, stream>>>(
        h, 80, 80, agg, 320, 320,
        Bt2 + i*99840, 416, 240, bias2 + i*80, h, nullptr, 80, NN, 416,
        scf, invf, 0, 0, 0);
  }

  k_poolmlp<<<NGR, 128, 0, stream>>>(h, batch, mlpW, mlpb, flag, d_out);
}